// Round 7
// baseline (206.185 us; speedup 1.0000x reference)
//
#include <hip/hip_runtime.h>

// QuantizedSpectralConv on MI355X (gfx950).
// x [8,32,256,256] f32; Tucker: core[16,16,16,9] F0[32,16] F1[32,16] F2[32,16]
// F3[17,9] complex, deq = q*scale+min. Active window: kx in [112,144),
// ky in [56,73) of the (256,129) rfft2. norm="forward" (1/65536 on fwd).
//
// Workspace (float2):
//   A1 [17 ky][256 bi][256 h]; X [544 mode][256 bi]; W4 [544][32][32];
//   Mx [544 mode][256 bo]
// LDS rule: addresses wave-uniform (broadcast) or lane-consecutive only.

__device__ __forceinline__ float2 cfma(float2 a, float2 b, float2 c) {
    c.x = fmaf(a.x, b.x, fmaf(-a.y, b.y, c.x));
    c.y = fmaf(a.x, b.y, fmaf(a.y, b.x, c.y));
    return c;
}
__device__ __forceinline__ float2 cmul(float2 a, float2 b) {
    return make_float2(a.x*b.x - a.y*b.y, a.x*b.y + a.y*b.x);
}

// ============ weights (wprep fused): W4 from quantized core+factors ==========
// C2[ij] = sum_{k,l} deq(core[ij,k,l]) * G[k,l],  G[k,l] = F2[c,k]*F3[d,l]
__global__ __launch_bounds__(256) void weights_kernel(
    const int* __restrict__ q_core, const int* __restrict__ q_f0,
    const int* __restrict__ q_f1, const int* __restrict__ q_f2,
    const int* __restrict__ q_f3,
    const float* __restrict__ core_scale, const float* __restrict__ core_min,
    const float* __restrict__ f_scales, const float* __restrict__ f_mins,
    float2* __restrict__ W4)
{
    __shared__ float2 F0s[512], F1s[512];
    __shared__ float2 Gs[144];
    __shared__ float2 C2p[16*17];
    __shared__ float2 A2p[16*33];
    int t = threadIdx.x, m = blockIdx.x;
    int c = m / 17, d = m % 17;
    float s0 = f_scales[0], m0 = f_mins[0];
    float s1 = f_scales[1], m1 = f_mins[1];
    float s2 = f_scales[2], m2 = f_mins[2];
    float s3 = f_scales[3], m3 = f_mins[3];
    float cs = *core_scale, cm = *core_min;

    for (int e = t; e < 512; e += 256) {
        F0s[e] = make_float2(q_f0[2*e]*s0 + m0, q_f0[2*e+1]*s0 + m0);
        F1s[e] = make_float2(q_f1[2*e]*s1 + m1, q_f1[2*e+1]*s1 + m1);
    }
    if (t < 144) {                      // G[k][l], t = k*9+l
        int k = t / 9, l = t - 9*k;
        float2 f2 = make_float2(q_f2[(c*16+k)*2]*s2 + m2,
                                q_f2[(c*16+k)*2+1]*s2 + m2);
        float2 f3 = make_float2(q_f3[(d*9+l)*2]*s3 + m3,
                                q_f3[(d*9+l)*2+1]*s3 + m3);
        Gs[t] = cmul(f2, f3);
    }
    __syncthreads();
    {   // phase 1: per-thread ij = t; core[ij] is thread-contiguous (72 int4)
        const int4* qc = (const int4*)(q_core + t*288);
        float2 acc = make_float2(0.f, 0.f);
#pragma unroll 8
        for (int p = 0; p < 72; ++p) {
            int4 q = qc[p];
            float2 ce0 = make_float2(q.x*cs + cm, q.y*cs + cm);
            float2 ce1 = make_float2(q.z*cs + cm, q.w*cs + cm);
            acc = cfma(ce0, Gs[2*p], acc);      // Gs reads wave-uniform
            acc = cfma(ce1, Gs[2*p+1], acc);
        }
        C2p[(t >> 4)*17 + (t & 15)] = acc;
    }
    __syncthreads();
#pragma unroll
    for (int r = 0; r < 2; ++r) {   // phase 2: A2[i,b] = sum_j C2[i,j]*F1[b,j]
        int e = t + r*256; int i = e & 15, b = e >> 4;
        float2 acc = make_float2(0.f, 0.f);
#pragma unroll
        for (int j = 0; j < 16; ++j)
            acc = cfma(C2p[i*17 + j], F1s[b*16 + j], acc);
        A2p[i*33 + b] = acc;
    }
    __syncthreads();
    {   // phase 3: W4[m,a,b] = sum_i F0[a,i]*A2[i,b]
        int b = t & 31, a0 = t >> 5;
#pragma unroll
        for (int q = 0; q < 4; ++q) {
            int a = a0 + 8*q;
            float2 acc = make_float2(0.f, 0.f);
#pragma unroll
            for (int i = 0; i < 16; ++i)
                acc = cfma(F0s[a*16 + i], A2p[i*33 + b], acc);
            W4[m*1024 + a*32 + b] = acc;
        }
    }
}

// ================= forward partial DFT along w =================
// Quadrant pre-combine + LDS twiddle table read as float4 pairs (2 wp per
// wave-uniform b128 -> half the twiddle LDS instructions of the b64 form).
// A(ky) = sum_{w'<64} T(ky,w') * y_r(w'),  r = ky mod 4:
//   y0 = (x0+x2)+(x1+x3)  (real)      y2 = (x0+x2)-(x1+x3)  (real)
//   y1 = d02 - i*d13                  y3 = d02 + i*d13
__global__ __launch_bounds__(256) void fwd_w_kernel(const float* __restrict__ x,
                                                    float2* __restrict__ A1)
{
    __shared__ float ys0[64*65], ys2[64*65], yd02[64*65], yd13[64*65];
    __shared__ __align__(16) float2 twl[17*64];   // [ki][w'], ki = ky-56
    int tid = threadIdx.x;
    int row0 = blockIdx.x * 64;

    for (int i = tid; i < 17*64; i += 256) {
        int ki = i >> 6, wp = i & 63;
        int n = ((56 + ki) * wp) & 255;
        float a = n * (1.f/128.f);
        twl[i] = make_float2(cospif(a), -sinpif(a));
    }
    const float2* xf2 = (const float2*)x;
    for (int i2 = tid; i2 < 2048; i2 += 256) {
        int r = i2 >> 5, w2 = i2 & 31;  // row, float2-index within quadrant
        const float2* xb = xf2 + (size_t)(row0 + r) * 128 + w2;
        float2 a0 = xb[0], a1 = xb[32], a2 = xb[64], a3 = xb[96];
        int ad = (2*w2)*65 + r;         // plane [w'][row], row-consecutive
        float s02 = a0.x + a2.x, s13 = a1.x + a3.x;
        ys0[ad] = s02 + s13;  ys2[ad] = s02 - s13;
        yd02[ad] = a0.x - a2.x;  yd13[ad] = a1.x - a3.x;
        s02 = a0.y + a2.y;  s13 = a1.y + a3.y;
        ys0[ad+65] = s02 + s13;  ys2[ad+65] = s02 - s13;
        yd02[ad+65] = a0.y - a2.y;  yd13[ad+65] = a1.y - a3.y;
    }
    __syncthreads();

    int lane = tid & 63, g = tid >> 6;  // wave g owns residue class g
    int row = row0 + lane;
    if (g == 0) {                       // ky = 56,60,64,68,72 : real y0
        float2 acc[5] = {};
#pragma unroll 2
        for (int wp = 0; wp < 64; wp += 2) {
            float ya = ys0[wp*65 + lane];
            float yb = ys0[(wp+1)*65 + lane];
#pragma unroll
            for (int j = 0; j < 5; ++j) {
                float4 tt = *(const float4*)&twl[(4*j)*64 + wp];
                acc[j].x = fmaf(ya, tt.x, fmaf(yb, tt.z, acc[j].x));
                acc[j].y = fmaf(ya, tt.y, fmaf(yb, tt.w, acc[j].y));
            }
        }
#pragma unroll
        for (int j = 0; j < 5; ++j) A1[(4*j)*65536 + row] = acc[j];
    } else if (g == 2) {                // ky = 58,62,66,70 : real y2
        float2 acc[4] = {};
#pragma unroll 2
        for (int wp = 0; wp < 64; wp += 2) {
            float ya = ys2[wp*65 + lane];
            float yb = ys2[(wp+1)*65 + lane];
#pragma unroll
            for (int j = 0; j < 4; ++j) {
                float4 tt = *(const float4*)&twl[(2+4*j)*64 + wp];
                acc[j].x = fmaf(ya, tt.x, fmaf(yb, tt.z, acc[j].x));
                acc[j].y = fmaf(ya, tt.y, fmaf(yb, tt.w, acc[j].y));
            }
        }
#pragma unroll
        for (int j = 0; j < 4; ++j) A1[(2+4*j)*65536 + row] = acc[j];
    } else if (g == 1) {                // ky = 57,61,65,69 : y1 = a - i b
        float2 acc[4] = {};
#pragma unroll 2
        for (int wp = 0; wp < 64; wp += 2) {
            float aa = yd02[wp*65 + lane],     ba = yd13[wp*65 + lane];
            float ab = yd02[(wp+1)*65 + lane], bb = yd13[(wp+1)*65 + lane];
#pragma unroll
            for (int j = 0; j < 4; ++j) {
                float4 tt = *(const float4*)&twl[(1+4*j)*64 + wp];
                acc[j].x = fmaf(tt.x, aa, fmaf( tt.y, ba,
                           fmaf(tt.z, ab, fmaf( tt.w, bb, acc[j].x))));
                acc[j].y = fmaf(tt.y, aa, fmaf(-tt.x, ba,
                           fmaf(tt.w, ab, fmaf(-tt.z, bb, acc[j].y))));
            }
        }
#pragma unroll
        for (int j = 0; j < 4; ++j) A1[(1+4*j)*65536 + row] = acc[j];
    } else {                            // ky = 59,63,67,71 : y3 = a + i b
        float2 acc[4] = {};
#pragma unroll 2
        for (int wp = 0; wp < 64; wp += 2) {
            float aa = yd02[wp*65 + lane],     ba = yd13[wp*65 + lane];
            float ab = yd02[(wp+1)*65 + lane], bb = yd13[(wp+1)*65 + lane];
#pragma unroll
            for (int j = 0; j < 4; ++j) {
                float4 tt = *(const float4*)&twl[(3+4*j)*64 + wp];
                acc[j].x = fmaf(tt.x, aa, fmaf(-tt.y, ba,
                           fmaf(tt.z, ab, fmaf(-tt.w, bb, acc[j].x))));
                acc[j].y = fmaf(tt.y, aa, fmaf( tt.x, ba,
                           fmaf(tt.w, ab, fmaf( tt.z, bb, acc[j].y))));
            }
        }
#pragma unroll
        for (int j = 0; j < 4; ++j) A1[(3+4*j)*65536 + row] = acc[j];
    }
}

// ================= forward partial DFT along h =================
__global__ __launch_bounds__(256) void fwd_h_kernel(const float2* __restrict__ A1,
                                                    float2* __restrict__ X)
{
    __shared__ float2 tbl[256];
    __shared__ float as_re[8*264];
    __shared__ float as_im[8*264];
    int tid = threadIdx.x;
    int ky = blockIdx.x >> 5, bi0 = (blockIdx.x & 31) * 8;
    tbl[tid] = make_float2(cospif(tid * (1.f/128.f)), -sinpif(tid * (1.f/128.f)));
    for (int idx = tid; idx < 2048; idx += 256) {
        int b = idx >> 8, h = idx & 255;
        float2 v = A1[ky*65536 + (bi0 + b)*256 + h];
        int ad = (h >> 5)*264 + (h & 31)*8 + b;
        as_re[ad] = v.x; as_im[ad] = v.y;
    }
    __syncthreads();
    int lane = tid & 63, g = tid >> 6;
    int bl = lane & 7, q = lane >> 3;
    int kx0 = g * 8;
    float2 acc[8];
#pragma unroll
    for (int j = 0; j < 8; ++j) acc[j] = make_float2(0.f, 0.f);
    int base = q*264 + bl;
    for (int hh = 0; hh < 32; ++hh) {
        float ar = as_re[base + hh*8];
        float ai = as_im[base + hh*8];
#pragma unroll
        for (int j = 0; j < 8; ++j) {
            int kk = kx0 + j + 112;
            float2 t = tbl[(kk * hh) & 255];      // wave-uniform broadcast
            acc[j].x = fmaf(ar, t.x, fmaf(-ai, t.y, acc[j].x));
            acc[j].y = fmaf(ar, t.y, fmaf( ai, t.x, acc[j].y));
        }
    }
    // epilogue twiddle e^{-2pi i jq/8} via recurrence; step from resident tbl
    float2 fstep = tbl[q * 32];                   // e^{-2pi i q/8}
    float2 f = make_float2(1.f, 0.f);
#pragma unroll
    for (int j = 0; j < 8; ++j) {
        float2 v = cmul(acc[j], f);
        v.x += __shfl_xor(v.x, 8);  v.y += __shfl_xor(v.y, 8);
        v.x += __shfl_xor(v.x, 16); v.y += __shfl_xor(v.y, 16);
        v.x += __shfl_xor(v.x, 32); v.y += __shfl_xor(v.y, 32);
        acc[j] = v;
        f = cmul(f, fstep);
    }
    if (q == 0) {
        const float inv = 1.f / 65536.f;
#pragma unroll
        for (int j = 0; j < 8; ++j)
            X[((kx0 + j)*17 + ky)*256 + bi0 + bl] =
                make_float2(acc[j].x * inv, acc[j].y * inv);
    }
}

// ================= per-mode channel mixing =================
__global__ __launch_bounds__(256) void mix_kernel(const float2* __restrict__ X,
                                                  const float2* __restrict__ W4,
                                                  float2* __restrict__ Mx)
{
    __shared__ float2 Xs[256];
    __shared__ float2 Ws[1024];
    int tid = threadIdx.x, mode = blockIdx.x;
    Xs[tid] = X[mode*256 + tid];
    for (int idx = tid; idx < 1024; idx += 256) Ws[idx] = W4[mode*1024 + idx];
    __syncthreads();
    int b = tid >> 5, o = tid & 31;
    float2 acc = make_float2(0.f, 0.f);
#pragma unroll
    for (int i = 0; i < 32; ++i)
        acc = cfma(Xs[b*32 + i], Ws[i*32 + o], acc);
    Mx[mode*256 + tid] = acc;
}

// ================= fused inverse =================
// Grid 2048 = bo(256) x hc(8); block covers 32 h x 256 w.
// Phase 1: wave-uniform runtime-ky form: 4 waves x {4,4,4,5} ky, two ky-slots
// per wave via lane>>5 (no half-wave EXEC serialization; 2-address LDS reads
// are a free 2-way broadcast). Twiddles by register recurrence.
__global__ __launch_bounds__(256) void inv_kernel(const float2* __restrict__ Mx,
                                                  const int* __restrict__ q_bias,
                                                  const float* __restrict__ b_scale,
                                                  const float* __restrict__ b_min,
                                                  float* __restrict__ out)
{
    __shared__ float2 ms[544];
    __shared__ __align__(16) float2 Ts[32*18];     // rows padded to 18
    int tid = threadIdx.x;
    int bo = blockIdx.x & 255, hc = blockIdx.x >> 8;
    for (int idx = tid; idx < 544; idx += 256) ms[idx] = Mx[idx*256 + bo];
    __syncthreads();
    {   // phase 1: Ts[hh][ky] = sum_kx ms[kx][ky] e^{+2pi i (kx+112)h/256}
        int lane = tid & 63, w = tid >> 6;         // wave id
        int hh = lane & 31, ks = lane >> 5;        // ky slot 0/1
        int h = hc*32 + hh;
        int n0 = (112 * h) & 255;
        float tr = cospif(n0 * (1.f/128.f)), ti = sinpif(n0 * (1.f/128.f));
        float sr = cospif(h  * (1.f/128.f)), si = sinpif(h  * (1.f/128.f));
        if (w < 3) {                               // ky = 4w+ks, 4w+ks+2
            int ky0 = 4*w + ks;
            float2 a0 = make_float2(0.f,0.f), a1 = make_float2(0.f,0.f);
            for (int kx = 0; kx < 32; ++kx) {
                const float2* mr = ms + kx*17;
                float2 v0 = mr[ky0], v1 = mr[ky0+2];
                a0.x = fmaf(v0.x, tr, fmaf(-v0.y, ti, a0.x));
                a0.y = fmaf(v0.x, ti, fmaf( v0.y, tr, a0.y));
                a1.x = fmaf(v1.x, tr, fmaf(-v1.y, ti, a1.x));
                a1.y = fmaf(v1.x, ti, fmaf( v1.y, tr, a1.y));
                float ntr = fmaf(tr, sr, -ti*si);
                ti = fmaf(tr, si, ti*sr);
                tr = ntr;
            }
            Ts[hh*18 + ky0]     = a0;
            Ts[hh*18 + ky0 + 2] = a1;
        } else {                                   // ky = 12+ks, 14+ks, (16)
            int ky0 = 12 + ks;
            int ky2 = ky0 + 4, ky2c = ky2 > 16 ? 16 : ky2;
            float2 a0 = make_float2(0.f,0.f), a1 = make_float2(0.f,0.f),
                   a2 = make_float2(0.f,0.f);
            for (int kx = 0; kx < 32; ++kx) {
                const float2* mr = ms + kx*17;
                float2 v0 = mr[ky0], v1 = mr[ky0+2], v2 = mr[ky2c];
                a0.x = fmaf(v0.x, tr, fmaf(-v0.y, ti, a0.x));
                a0.y = fmaf(v0.x, ti, fmaf( v0.y, tr, a0.y));
                a1.x = fmaf(v1.x, tr, fmaf(-v1.y, ti, a1.x));
                a1.y = fmaf(v1.x, ti, fmaf( v1.y, tr, a1.y));
                a2.x = fmaf(v2.x, tr, fmaf(-v2.y, ti, a2.x));
                a2.y = fmaf(v2.x, ti, fmaf( v2.y, tr, a2.y));
                float ntr = fmaf(tr, sr, -ti*si);
                ti = fmaf(tr, si, ti*sr);
                tr = ntr;
            }
            Ts[hh*18 + ky0]     = a0;
            Ts[hh*18 + ky0 + 2] = a1;
            if (ky2 < 17) Ts[hh*18 + ky2] = a2;
        }
    }
    __syncthreads();
    {   // phase 2: out[h][w0+64q] = 2*Re(T[h]*e^{i th0}*i^{ky*q}) + bias
        int w0 = tid & 63, hs = tid >> 6;          // 4 h-subgroups of 8
        // C[ky]+iS[ky] = e^{+2pi i (ky+56) w0 / 256} via recurrence
        float C[17], S[17];
        {
            int n0 = (56 * w0) & 255;
            float tr = cospif(n0 * (1.f/128.f)), ti = sinpif(n0 * (1.f/128.f));
            float sr = cospif(w0 * (1.f/128.f)), si = sinpif(w0 * (1.f/128.f));
#pragma unroll
            for (int ky = 0; ky < 17; ++ky) {
                C[ky] = tr; S[ky] = ti;
                float ntr = fmaf(tr, sr, -ti*si);
                ti = fmaf(tr, si, ti*sr);
                tr = ntr;
            }
        }
        float bias = q_bias[bo & 31] * (*b_scale) + (*b_min);
        float* obase = out + (size_t)bo*65536 + (size_t)hc*32*256;

#pragma unroll
        for (int r = 0; r < 8; ++r) {
            int hh = hs*8 + r;
            const float4* tp = (const float4*)&Ts[hh*18];
            // residue-class accumulators: contribution of ky to quadrant q is
            // one of {+ur,-ui,-ur,+ui} keyed by p=(ky*q)&3; even ky never needs ui.
            float R0 = 0.f, R1 = 0.f, R2 = 0.f, R3 = 0.f, I1 = 0.f, I3 = 0.f;
#pragma unroll
            for (int kp = 0; kp < 9; ++kp) {
                float vx0, vy0, vx1 = 0.f, vy1 = 0.f;
                if (kp < 8) {
                    float4 v4 = tp[kp];
                    vx0 = v4.x; vy0 = v4.y; vx1 = v4.z; vy1 = v4.w;
                } else {
                    float2 v2 = Ts[hh*18 + 16];
                    vx0 = v2.x; vy0 = v2.y;
                }
#pragma unroll
                for (int half = 0; half < 2; ++half) {
                    if (kp == 8 && half == 1) break;
                    const int ky = 2*kp + half;
                    float vx = half ? vx1 : vx0;
                    float vy = half ? vy1 : vy0;
                    float ur = fmaf(vx, C[ky], -vy*S[ky]);
                    if ((ky & 1) == 0) {
                        if ((ky & 3) == 0) R0 += ur; else R2 += ur;
                    } else {
                        float ui = fmaf(vx, S[ky], vy*C[ky]);
                        if ((ky & 3) == 1) { R1 += ur; I1 += ui; }
                        else               { R3 += ur; I3 += ui; }
                    }
                }
            }
            // combine: q0=R0+R1+R2+R3; q1=R0-I1-R2+I3; q2=R0-R1+R2-R3; q3=R0+I1-R2-I3
            float e02 = R0 + R2, d02 = R0 - R2;
            float e13 = R1 + R3, di  = I3 - I1;
            float q0 = e02 + e13, q2 = e02 - e13;
            float q1 = d02 + di,  q3 = d02 - di;
            obase[hh*256 + w0]       = fmaf(2.f, q0, bias);
            obase[hh*256 + w0 + 64]  = fmaf(2.f, q1, bias);
            obase[hh*256 + w0 + 128] = fmaf(2.f, q2, bias);
            obase[hh*256 + w0 + 192] = fmaf(2.f, q3, bias);
        }
    }
}

extern "C" void kernel_launch(void* const* d_in, const int* in_sizes, int n_in,
                              void* d_out, int out_size, void* d_ws, size_t ws_size,
                              hipStream_t stream) {
    const float* x          = (const float*)d_in[0];
    const float* core_scale = (const float*)d_in[1];
    const float* core_min   = (const float*)d_in[2];
    const float* f_scales   = (const float*)d_in[3];
    const float* f_mins     = (const float*)d_in[4];
    const float* b_scale    = (const float*)d_in[5];
    const float* b_min      = (const float*)d_in[6];
    const int* q_core = (const int*)d_in[7];
    const int* q_f0   = (const int*)d_in[8];
    const int* q_f1   = (const int*)d_in[9];
    const int* q_f2   = (const int*)d_in[10];
    const int* q_f3   = (const int*)d_in[11];
    const int* q_bias = (const int*)d_in[12];
    float* out = (float*)d_out;

    float2* ws = (float2*)d_ws;
    float2* A1 = ws;                 // 1,114,112  [17][256 bi][256 h]
    float2* W4 = ws + 1114112;       //   557,056  [544][32][32]
    float2* X  = W4 + 557056;        //   139,264  [544][256]
    float2* Mx = X + 139264;         //   139,264  [544][256]
    (void)ws_size; (void)n_in; (void)in_sizes; (void)out_size;

    weights_kernel<<<544, 256, 0, stream>>>(q_core, q_f0, q_f1, q_f2, q_f3,
                                            core_scale, core_min,
                                            f_scales, f_mins, W4);
    fwd_w_kernel<<<1024, 256, 0, stream>>>(x, A1);
    fwd_h_kernel<<<544, 256, 0, stream>>>(A1, X);
    mix_kernel<<<544, 256, 0, stream>>>(X, W4, Mx);
    inv_kernel<<<2048, 256, 0, stream>>>(Mx, q_bias, b_scale, b_min, out);
}

// Round 8
// 193.874 us; speedup vs baseline: 1.0635x; 1.0635x over previous
//
#include <hip/hip_runtime.h>

// QuantizedSpectralConv on MI355X (gfx950).
// x [8,32,256,256] f32; Tucker: core[16,16,16,9] F0[32,16] F1[32,16] F2[32,16]
// F3[17,9] complex, deq = q*scale+min. Active window: kx in [112,144),
// ky in [56,73) of the (256,129) rfft2. norm="forward" (1/65536 on fwd).
//
// Workspace (float2):
//   A1 [17 ky][256 bi][256 h]; X [544 mode][256 bi]; W4 [544][32][32];
//   Mx [544 mode][256 bo];     CL [17 d][16 k][256 ij]  (F3-contracted core)
// LDS rule: addresses wave-uniform (broadcast) or lane-consecutive only.

__device__ __forceinline__ float2 cfma(float2 a, float2 b, float2 c) {
    c.x = fmaf(a.x, b.x, fmaf(-a.y, b.y, c.x));
    c.y = fmaf(a.x, b.y, fmaf(a.y, b.x, c.y));
    return c;
}
__device__ __forceinline__ float2 cmul(float2 a, float2 b) {
    return make_float2(a.x*b.x - a.y*b.y, a.x*b.y + a.y*b.x);
}

// ============ wprep: CL[d][k][ij] = sum_l core[ij,k,l] * F3[d,l] ============
__global__ __launch_bounds__(256) void wprep_kernel(
    const int* __restrict__ q_core, const int* __restrict__ q_f3,
    const float* __restrict__ core_scale, const float* __restrict__ core_min,
    const float* __restrict__ f_scales, const float* __restrict__ f_mins,
    float2* __restrict__ CL)
{
    int d = blockIdx.x >> 4, k = blockIdx.x & 15;   // grid 272
    int ij = threadIdx.x;
    float cs = *core_scale, cm = *core_min;
    float s3 = f_scales[3], m3 = f_mins[3];
    const int* qc = q_core + ((ij*16 + k)*9)*2;
    float2 acc = make_float2(0.f, 0.f);
#pragma unroll
    for (int l = 0; l < 9; ++l) {
        int2 q = *(const int2*)(qc + l*2);
        float2 ce = make_float2(q.x*cs + cm, q.y*cs + cm);
        float2 f3 = make_float2(q_f3[(d*9+l)*2]*s3 + m3, q_f3[(d*9+l)*2+1]*s3 + m3);
        acc = cfma(ce, f3, acc);
    }
    CL[(d*16 + k)*256 + ij] = acc;
}

// ============ weights: per-mode k/j/i contractions, CL coalesced ============
__global__ __launch_bounds__(256) void weights_kernel(
    const float2* __restrict__ CL, const int* __restrict__ q_f0,
    const int* __restrict__ q_f1, const int* __restrict__ q_f2,
    const float* __restrict__ f_scales, const float* __restrict__ f_mins,
    float2* __restrict__ W4)
{
    __shared__ float2 F0s[512], F1s[512];
    __shared__ float2 C2p[16*17];
    __shared__ float2 A2p[16*33];
    int t = threadIdx.x, m = blockIdx.x;
    int c = m / 17, d = m % 17;
    float s0 = f_scales[0], m0 = f_mins[0];
    float s1 = f_scales[1], m1 = f_mins[1];
    float s2 = f_scales[2], m2 = f_mins[2];

    for (int e = t; e < 512; e += 256) {
        F0s[e] = make_float2(q_f0[2*e]*s0 + m0, q_f0[2*e+1]*s0 + m0);
        F1s[e] = make_float2(q_f1[2*e]*s1 + m1, q_f1[2*e+1]*s1 + m1);
    }
    {   // phase 1: C2[i,j] = sum_k CL[d][k][ij] * F2[c,k]   (coalesced reads)
        float2 acc = make_float2(0.f, 0.f);
#pragma unroll
        for (int k = 0; k < 16; ++k) {
            float2 clv = CL[(d*16 + k)*256 + t];
            float2 f2 = make_float2(q_f2[(c*16+k)*2]*s2 + m2,
                                    q_f2[(c*16+k)*2+1]*s2 + m2);
            acc = cfma(clv, f2, acc);
        }
        __syncthreads();            // F0s/F1s ready; also before C2p write is fine
        C2p[(t >> 4)*17 + (t & 15)] = acc;
    }
    __syncthreads();
#pragma unroll
    for (int r = 0; r < 2; ++r) {   // phase 2: A2[i,b] = sum_j C2[i,j]*F1[b,j]
        int e = t + r*256; int i = e & 15, b = e >> 4;
        float2 acc = make_float2(0.f, 0.f);
#pragma unroll
        for (int j = 0; j < 16; ++j)
            acc = cfma(C2p[i*17 + j], F1s[b*16 + j], acc);
        A2p[i*33 + b] = acc;
    }
    __syncthreads();
    {   // phase 3: W4[m,a,b] = sum_i F0[a,i]*A2[i,b]
        int b = t & 31, a0 = t >> 5;
#pragma unroll
        for (int q = 0; q < 4; ++q) {
            int a = a0 + 8*q;
            float2 acc = make_float2(0.f, 0.f);
#pragma unroll
            for (int i = 0; i < 16; ++i)
                acc = cfma(F0s[a*16 + i], A2p[i*33 + b], acc);
            W4[m*1024 + a*32 + b] = acc;
        }
    }
}

// ================= forward partial DFT along w =================
// Quadrant pre-combine; LDS ops PAIRED over w': y-planes stored as float2
// wp-pairs (1 ds_read_b64 for 2 w'), twiddles read as wave-uniform float4
// (2 w' per b128). Halves main-loop LDS instruction count vs the b32/b64
// form -- fwd_w is LDS-instruction-issue bound at 2 blocks/CU.
// A(ky) = sum_{w'<64} T(ky,w') * y_r(w'),  r = ky mod 4:
//   y0 = (x0+x2)+(x1+x3)  (real)      y2 = (x0+x2)-(x1+x3)  (real)
//   y1 = d02 - i*d13                  y3 = d02 + i*d13
__global__ __launch_bounds__(256) void fwd_w_kernel(const float* __restrict__ x,
                                                    float2* __restrict__ A1)
{
    __shared__ float2 ysp0[32*65], ysp2[32*65], ydp02[32*65], ydp13[32*65];
    __shared__ __align__(16) float2 twl[17*64];   // [ki][w'], ki = ky-56
    int tid = threadIdx.x;
    int row0 = blockIdx.x * 64;

    for (int i = tid; i < 17*64; i += 256) {
        int ki = i >> 6, wp = i & 63;
        int n = ((56 + ki) * wp) & 255;
        float a = n * (1.f/128.f);
        twl[i] = make_float2(cospif(a), -sinpif(a));
    }
    const float2* xf2 = (const float2*)x;
    for (int i2 = tid; i2 < 2048; i2 += 256) {
        int r = i2 >> 5, w2 = i2 & 31;  // row, wp-pair index
        const float2* xb = xf2 + (size_t)(row0 + r) * 128 + w2;
        float2 a0 = xb[0], a1 = xb[32], a2 = xb[64], a3 = xb[96];
        int ad = w2*65 + r;             // [wp2][row], row-consecutive
        float s02a = a0.x + a2.x, s13a = a1.x + a3.x;
        float s02b = a0.y + a2.y, s13b = a1.y + a3.y;
        ysp0[ad]  = make_float2(s02a + s13a, s02b + s13b);
        ysp2[ad]  = make_float2(s02a - s13a, s02b - s13b);
        ydp02[ad] = make_float2(a0.x - a2.x, a0.y - a2.y);
        ydp13[ad] = make_float2(a1.x - a3.x, a1.y - a3.y);
    }
    __syncthreads();

    int lane = tid & 63, g = tid >> 6;  // wave g owns residue class g
    int row = row0 + lane;
    if (g == 0) {                       // ky = 56,60,64,68,72 : real y0
        float2 acc[5] = {};
#pragma unroll 4
        for (int wp2 = 0; wp2 < 32; ++wp2) {
            float2 y = ysp0[wp2*65 + lane];
#pragma unroll
            for (int j = 0; j < 5; ++j) {
                float4 tt = *(const float4*)&twl[(4*j)*64 + 2*wp2];
                acc[j].x = fmaf(y.x, tt.x, fmaf(y.y, tt.z, acc[j].x));
                acc[j].y = fmaf(y.x, tt.y, fmaf(y.y, tt.w, acc[j].y));
            }
        }
#pragma unroll
        for (int j = 0; j < 5; ++j) A1[(4*j)*65536 + row] = acc[j];
    } else if (g == 2) {                // ky = 58,62,66,70 : real y2
        float2 acc[4] = {};
#pragma unroll 4
        for (int wp2 = 0; wp2 < 32; ++wp2) {
            float2 y = ysp2[wp2*65 + lane];
#pragma unroll
            for (int j = 0; j < 4; ++j) {
                float4 tt = *(const float4*)&twl[(2+4*j)*64 + 2*wp2];
                acc[j].x = fmaf(y.x, tt.x, fmaf(y.y, tt.z, acc[j].x));
                acc[j].y = fmaf(y.x, tt.y, fmaf(y.y, tt.w, acc[j].y));
            }
        }
#pragma unroll
        for (int j = 0; j < 4; ++j) A1[(2+4*j)*65536 + row] = acc[j];
    } else if (g == 1) {                // ky = 57,61,65,69 : y1 = a - i b
        float2 acc[4] = {};
#pragma unroll 4
        for (int wp2 = 0; wp2 < 32; ++wp2) {
            float2 a = ydp02[wp2*65 + lane];
            float2 b = ydp13[wp2*65 + lane];
#pragma unroll
            for (int j = 0; j < 4; ++j) {
                float4 tt = *(const float4*)&twl[(1+4*j)*64 + 2*wp2];
                acc[j].x = fmaf(tt.x, a.x, fmaf( tt.y, b.x,
                           fmaf(tt.z, a.y, fmaf( tt.w, b.y, acc[j].x))));
                acc[j].y = fmaf(tt.y, a.x, fmaf(-tt.x, b.x,
                           fmaf(tt.w, a.y, fmaf(-tt.z, b.y, acc[j].y))));
            }
        }
#pragma unroll
        for (int j = 0; j < 4; ++j) A1[(1+4*j)*65536 + row] = acc[j];
    } else {                            // ky = 59,63,67,71 : y3 = a + i b
        float2 acc[4] = {};
#pragma unroll 4
        for (int wp2 = 0; wp2 < 32; ++wp2) {
            float2 a = ydp02[wp2*65 + lane];
            float2 b = ydp13[wp2*65 + lane];
#pragma unroll
            for (int j = 0; j < 4; ++j) {
                float4 tt = *(const float4*)&twl[(3+4*j)*64 + 2*wp2];
                acc[j].x = fmaf(tt.x, a.x, fmaf(-tt.y, b.x,
                           fmaf(tt.z, a.y, fmaf(-tt.w, b.y, acc[j].x))));
                acc[j].y = fmaf(tt.y, a.x, fmaf( tt.x, b.x,
                           fmaf(tt.w, a.y, fmaf( tt.z, b.y, acc[j].y))));
            }
        }
#pragma unroll
        for (int j = 0; j < 4; ++j) A1[(3+4*j)*65536 + row] = acc[j];
    }
}

// ================= forward partial DFT along h =================
__global__ __launch_bounds__(256) void fwd_h_kernel(const float2* __restrict__ A1,
                                                    float2* __restrict__ X)
{
    __shared__ float2 tbl[256];
    __shared__ float as_re[8*264];
    __shared__ float as_im[8*264];
    int tid = threadIdx.x;
    int ky = blockIdx.x >> 5, bi0 = (blockIdx.x & 31) * 8;
    tbl[tid] = make_float2(cospif(tid * (1.f/128.f)), -sinpif(tid * (1.f/128.f)));
    for (int idx = tid; idx < 2048; idx += 256) {
        int b = idx >> 8, h = idx & 255;
        float2 v = A1[ky*65536 + (bi0 + b)*256 + h];
        int ad = (h >> 5)*264 + (h & 31)*8 + b;
        as_re[ad] = v.x; as_im[ad] = v.y;
    }
    __syncthreads();
    int lane = tid & 63, g = tid >> 6;
    int bl = lane & 7, q = lane >> 3;
    int kx0 = g * 8;
    float2 acc[8];
#pragma unroll
    for (int j = 0; j < 8; ++j) acc[j] = make_float2(0.f, 0.f);
    int base = q*264 + bl;
    for (int hh = 0; hh < 32; ++hh) {
        float ar = as_re[base + hh*8];
        float ai = as_im[base + hh*8];
#pragma unroll
        for (int j = 0; j < 8; ++j) {
            int kk = kx0 + j + 112;
            float2 t = tbl[(kk * hh) & 255];      // wave-uniform broadcast
            acc[j].x = fmaf(ar, t.x, fmaf(-ai, t.y, acc[j].x));
            acc[j].y = fmaf(ar, t.y, fmaf( ai, t.x, acc[j].y));
        }
    }
    // epilogue twiddle e^{-2pi i jq/8} via recurrence; step from resident tbl
    float2 fstep = tbl[q * 32];                   // e^{-2pi i q/8}
    float2 f = make_float2(1.f, 0.f);
#pragma unroll
    for (int j = 0; j < 8; ++j) {
        float2 v = cmul(acc[j], f);
        v.x += __shfl_xor(v.x, 8);  v.y += __shfl_xor(v.y, 8);
        v.x += __shfl_xor(v.x, 16); v.y += __shfl_xor(v.y, 16);
        v.x += __shfl_xor(v.x, 32); v.y += __shfl_xor(v.y, 32);
        acc[j] = v;
        f = cmul(f, fstep);
    }
    if (q == 0) {
        const float inv = 1.f / 65536.f;
#pragma unroll
        for (int j = 0; j < 8; ++j)
            X[((kx0 + j)*17 + ky)*256 + bi0 + bl] =
                make_float2(acc[j].x * inv, acc[j].y * inv);
    }
}

// ================= per-mode channel mixing =================
__global__ __launch_bounds__(256) void mix_kernel(const float2* __restrict__ X,
                                                  const float2* __restrict__ W4,
                                                  float2* __restrict__ Mx)
{
    __shared__ float2 Xs[256];
    __shared__ float2 Ws[1024];
    int tid = threadIdx.x, mode = blockIdx.x;
    Xs[tid] = X[mode*256 + tid];
    for (int idx = tid; idx < 1024; idx += 256) Ws[idx] = W4[mode*1024 + idx];
    __syncthreads();
    int b = tid >> 5, o = tid & 31;
    float2 acc = make_float2(0.f, 0.f);
#pragma unroll
    for (int i = 0; i < 32; ++i)
        acc = cfma(Xs[b*32 + i], Ws[i*32 + o], acc);
    Mx[mode*256 + tid] = acc;
}

// ================= fused inverse, w-quadrant registers =================
// Grid 2048 = bo(256) x hc(8); block covers 32 h x 256 w.
// Phase 1 twiddles via per-thread recurrence (4 libm trig at init instead of
// 64 in-loop sincospi). Phase 2 C/S via recurrence, residue-class accumulate.
template<int KY0, int NK>
__device__ __forceinline__ void invh_part(int h, int hh, const float2* ms, float2* Ts)
{
    float2 acc[NK];
#pragma unroll
    for (int j = 0; j < NK; ++j) acc[j] = make_float2(0.f, 0.f);
    // t = e^{+2pi i (kx+112) h / 256}: init at kx=0, step e^{+2pi i h/256}
    int n0 = (112 * h) & 255;
    float tr = cospif(n0 * (1.f/128.f)), ti = sinpif(n0 * (1.f/128.f));
    float sr = cospif(h  * (1.f/128.f)), si = sinpif(h  * (1.f/128.f));
    for (int kx = 0; kx < 32; ++kx) {
#pragma unroll
        for (int j = 0; j < NK; ++j) {
            float2 mv = ms[kx*17 + KY0 + j];       // 2-way broadcast
            acc[j].x = fmaf(mv.x, tr, fmaf(-mv.y, ti, acc[j].x));
            acc[j].y = fmaf(mv.x, ti, fmaf( mv.y, tr, acc[j].y));
        }
        float ntr = fmaf(tr, sr, -ti*si);          // t *= step
        ti = fmaf(tr, si, ti*sr);
        tr = ntr;
    }
#pragma unroll
    for (int j = 0; j < NK; ++j) Ts[hh*18 + KY0 + j] = acc[j];
}

__global__ __launch_bounds__(256) void inv_kernel(const float2* __restrict__ Mx,
                                                  const int* __restrict__ q_bias,
                                                  const float* __restrict__ b_scale,
                                                  const float* __restrict__ b_min,
                                                  float* __restrict__ out)
{
    __shared__ float2 ms[544];
    __shared__ __align__(16) float2 Ts[32*18];     // rows padded to 18
    int tid = threadIdx.x;
    int bo = blockIdx.x & 255, hc = blockIdx.x >> 8;
    for (int idx = tid; idx < 544; idx += 256) ms[idx] = Mx[idx*256 + bo];
    __syncthreads();
    {   // phase 1: Ts[hh][ky] = sum_kx ms[kx][ky] e^{+2pi i (kx+112)h/256}
        int hh = tid & 31, g = tid >> 5;           // g in [0,8)
        int h = hc*32 + hh;
        if (g < 7) {
            switch (g) {
                case 0: invh_part<0, 2>(h, hh, ms, Ts); break;
                case 1: invh_part<2, 2>(h, hh, ms, Ts); break;
                case 2: invh_part<4, 2>(h, hh, ms, Ts); break;
                case 3: invh_part<6, 2>(h, hh, ms, Ts); break;
                case 4: invh_part<8, 2>(h, hh, ms, Ts); break;
                case 5: invh_part<10,2>(h, hh, ms, Ts); break;
                default:invh_part<12,2>(h, hh, ms, Ts); break;
            }
        } else {
            invh_part<14,3>(h, hh, ms, Ts);
        }
    }
    __syncthreads();
    {   // phase 2: out[h][w0+64q] = 2*Re(T[h]*e^{i th0}*i^{ky*q}) + bias
        int w0 = tid & 63, hs = tid >> 6;          // 4 h-subgroups of 8
        // C[ky]+iS[ky] = e^{+2pi i (ky+56) w0 / 256} via recurrence
        float C[17], S[17];
        {
            int n0 = (56 * w0) & 255;
            float tr = cospif(n0 * (1.f/128.f)), ti = sinpif(n0 * (1.f/128.f));
            float sr = cospif(w0 * (1.f/128.f)), si = sinpif(w0 * (1.f/128.f));
#pragma unroll
            for (int ky = 0; ky < 17; ++ky) {
                C[ky] = tr; S[ky] = ti;
                float ntr = fmaf(tr, sr, -ti*si);
                ti = fmaf(tr, si, ti*sr);
                tr = ntr;
            }
        }
        float bias = q_bias[bo & 31] * (*b_scale) + (*b_min);
        float* obase = out + (size_t)bo*65536 + (size_t)hc*32*256;

#pragma unroll
        for (int r = 0; r < 8; ++r) {
            int hh = hs*8 + r;
            const float4* tp = (const float4*)&Ts[hh*18];
            // residue-class accumulators: contribution of ky to quadrant q is
            // one of {+ur,-ui,-ur,+ui} keyed by p=(ky*q)&3; even ky never needs ui.
            float R0 = 0.f, R1 = 0.f, R2 = 0.f, R3 = 0.f, I1 = 0.f, I3 = 0.f;
#pragma unroll
            for (int kp = 0; kp < 9; ++kp) {
                float vx0, vy0, vx1 = 0.f, vy1 = 0.f;
                if (kp < 8) {
                    float4 v4 = tp[kp];
                    vx0 = v4.x; vy0 = v4.y; vx1 = v4.z; vy1 = v4.w;
                } else {
                    float2 v2 = Ts[hh*18 + 16];
                    vx0 = v2.x; vy0 = v2.y;
                }
#pragma unroll
                for (int half = 0; half < 2; ++half) {
                    if (kp == 8 && half == 1) break;
                    const int ky = 2*kp + half;
                    float vx = half ? vx1 : vx0;
                    float vy = half ? vy1 : vy0;
                    float ur = fmaf(vx, C[ky], -vy*S[ky]);
                    if ((ky & 1) == 0) {
                        if ((ky & 3) == 0) R0 += ur; else R2 += ur;
                    } else {
                        float ui = fmaf(vx, S[ky], vy*C[ky]);
                        if ((ky & 3) == 1) { R1 += ur; I1 += ui; }
                        else               { R3 += ur; I3 += ui; }
                    }
                }
            }
            // combine: q0=R0+R1+R2+R3; q1=R0-I1-R2+I3; q2=R0-R1+R2-R3; q3=R0+I1-R2-I3
            float e02 = R0 + R2, d02 = R0 - R2;
            float e13 = R1 + R3, di  = I3 - I1;
            float q0 = e02 + e13, q2 = e02 - e13;
            float q1 = d02 + di,  q3 = d02 - di;
            obase[hh*256 + w0]       = fmaf(2.f, q0, bias);
            obase[hh*256 + w0 + 64]  = fmaf(2.f, q1, bias);
            obase[hh*256 + w0 + 128] = fmaf(2.f, q2, bias);
            obase[hh*256 + w0 + 192] = fmaf(2.f, q3, bias);
        }
    }
}

extern "C" void kernel_launch(void* const* d_in, const int* in_sizes, int n_in,
                              void* d_out, int out_size, void* d_ws, size_t ws_size,
                              hipStream_t stream) {
    const float* x          = (const float*)d_in[0];
    const float* core_scale = (const float*)d_in[1];
    const float* core_min   = (const float*)d_in[2];
    const float* f_scales   = (const float*)d_in[3];
    const float* f_mins     = (const float*)d_in[4];
    const float* b_scale    = (const float*)d_in[5];
    const float* b_min      = (const float*)d_in[6];
    const int* q_core = (const int*)d_in[7];
    const int* q_f0   = (const int*)d_in[8];
    const int* q_f1   = (const int*)d_in[9];
    const int* q_f2   = (const int*)d_in[10];
    const int* q_f3   = (const int*)d_in[11];
    const int* q_bias = (const int*)d_in[12];
    float* out = (float*)d_out;

    float2* ws = (float2*)d_ws;
    float2* A1 = ws;                 // 1,114,112  [17][256 bi][256 h]
    float2* W4 = ws + 1114112;       //   557,056  [544][32][32]
    float2* X  = W4 + 557056;        //   139,264  [544][256]
    float2* Mx = X + 139264;         //   139,264  [544][256]
    float2* CL = Mx + 139264;        //    69,632  [17][16][256]
    (void)ws_size; (void)n_in; (void)in_sizes; (void)out_size;

    wprep_kernel<<<272, 256, 0, stream>>>(q_core, q_f3, core_scale, core_min,
                                          f_scales, f_mins, CL);
    weights_kernel<<<544, 256, 0, stream>>>(CL, q_f0, q_f1, q_f2,
                                            f_scales, f_mins, W4);
    fwd_w_kernel<<<1024, 256, 0, stream>>>(x, A1);
    fwd_h_kernel<<<544, 256, 0, stream>>>(A1, X);
    mix_kernel<<<544, 256, 0, stream>>>(X, W4, Mx);
    inv_kernel<<<2048, 256, 0, stream>>>(Mx, q_bias, b_scale, b_min, out);
}

// Round 9
// 186.205 us; speedup vs baseline: 1.1073x; 1.0412x over previous
//
#include <hip/hip_runtime.h>

// QuantizedSpectralConv on MI355X (gfx950).
// x [8,32,256,256] f32; Tucker: core[16,16,16,9] F0[32,16] F1[32,16] F2[32,16]
// F3[17,9] complex, deq = q*scale+min. Active window: kx in [112,144),
// ky in [56,73) of the (256,129) rfft2. norm="forward" (1/65536 on fwd).
//
// Dispatch plan (horizontal fusion of independent stages, 4 launches):
//   K1 = wprep(272) ∪ fwd_w(1024)   -- independent chains
//   K2 = weights(544) ∪ fwd_h(544)  -- each depends only on K1
//   K3 = mix(544); K4 = inv(2048)
// Workspace (float2):
//   A1 [17 ky][256 bi][256 h]; X [544 mode][256 bi]; W4 [544][32][32];
//   Mx [544 mode][256 bo];     CL [17 d][16 k][256 ij]
// LDS rule: addresses wave-uniform (broadcast) or lane-consecutive only.

__device__ __forceinline__ float2 cfma(float2 a, float2 b, float2 c) {
    c.x = fmaf(a.x, b.x, fmaf(-a.y, b.y, c.x));
    c.y = fmaf(a.x, b.y, fmaf(a.y, b.x, c.y));
    return c;
}
__device__ __forceinline__ float2 cmul(float2 a, float2 b) {
    return make_float2(a.x*b.x - a.y*b.y, a.x*b.y + a.y*b.x);
}

// ============ wprep body: CL[d][k][ij] = sum_l core[ij,k,l] * F3[d,l] ========
__device__ __forceinline__ void wprep_body(
    int bid, const int* __restrict__ q_core, const int* __restrict__ q_f3,
    const float* __restrict__ core_scale, const float* __restrict__ core_min,
    const float* __restrict__ f_scales, const float* __restrict__ f_mins,
    float2* __restrict__ CL)
{
    int d = bid >> 4, k = bid & 15;
    int ij = threadIdx.x;
    float cs = *core_scale, cm = *core_min;
    float s3 = f_scales[3], m3 = f_mins[3];
    const int* qc = q_core + ((ij*16 + k)*9)*2;
    float2 acc = make_float2(0.f, 0.f);
#pragma unroll
    for (int l = 0; l < 9; ++l) {
        int2 q = *(const int2*)(qc + l*2);
        float2 ce = make_float2(q.x*cs + cm, q.y*cs + cm);
        float2 f3 = make_float2(q_f3[(d*9+l)*2]*s3 + m3, q_f3[(d*9+l)*2+1]*s3 + m3);
        acc = cfma(ce, f3, acc);
    }
    CL[(d*16 + k)*256 + ij] = acc;
}

// ================= fwd_w body: partial DFT along w =================
// Quadrant pre-combine; LDS ops paired over w' (b64 y-pairs, b128 twiddles).
__device__ __forceinline__ void fwdw_body(
    int bid, const float* __restrict__ x, float2* __restrict__ A1)
{
    __shared__ float2 ysp0[32*65], ysp2[32*65], ydp02[32*65], ydp13[32*65];
    __shared__ __align__(16) float2 twl[17*64];   // [ki][w'], ki = ky-56
    int tid = threadIdx.x;
    int row0 = bid * 64;

    for (int i = tid; i < 17*64; i += 256) {
        int ki = i >> 6, wp = i & 63;
        int n = ((56 + ki) * wp) & 255;
        float a = n * (1.f/128.f);
        twl[i] = make_float2(cospif(a), -sinpif(a));
    }
    const float2* xf2 = (const float2*)x;
    for (int i2 = tid; i2 < 2048; i2 += 256) {
        int r = i2 >> 5, w2 = i2 & 31;  // row, wp-pair index
        const float2* xb = xf2 + (size_t)(row0 + r) * 128 + w2;
        float2 a0 = xb[0], a1 = xb[32], a2 = xb[64], a3 = xb[96];
        int ad = w2*65 + r;             // [wp2][row], row-consecutive
        float s02a = a0.x + a2.x, s13a = a1.x + a3.x;
        float s02b = a0.y + a2.y, s13b = a1.y + a3.y;
        ysp0[ad]  = make_float2(s02a + s13a, s02b + s13b);
        ysp2[ad]  = make_float2(s02a - s13a, s02b - s13b);
        ydp02[ad] = make_float2(a0.x - a2.x, a0.y - a2.y);
        ydp13[ad] = make_float2(a1.x - a3.x, a1.y - a3.y);
    }
    __syncthreads();

    int lane = tid & 63, g = tid >> 6;  // wave g owns residue class g
    int row = row0 + lane;
    if (g == 0) {                       // ky = 56,60,64,68,72 : real y0
        float2 acc[5] = {};
#pragma unroll 4
        for (int wp2 = 0; wp2 < 32; ++wp2) {
            float2 y = ysp0[wp2*65 + lane];
#pragma unroll
            for (int j = 0; j < 5; ++j) {
                float4 tt = *(const float4*)&twl[(4*j)*64 + 2*wp2];
                acc[j].x = fmaf(y.x, tt.x, fmaf(y.y, tt.z, acc[j].x));
                acc[j].y = fmaf(y.x, tt.y, fmaf(y.y, tt.w, acc[j].y));
            }
        }
#pragma unroll
        for (int j = 0; j < 5; ++j) A1[(4*j)*65536 + row] = acc[j];
    } else if (g == 2) {                // ky = 58,62,66,70 : real y2
        float2 acc[4] = {};
#pragma unroll 4
        for (int wp2 = 0; wp2 < 32; ++wp2) {
            float2 y = ysp2[wp2*65 + lane];
#pragma unroll
            for (int j = 0; j < 4; ++j) {
                float4 tt = *(const float4*)&twl[(2+4*j)*64 + 2*wp2];
                acc[j].x = fmaf(y.x, tt.x, fmaf(y.y, tt.z, acc[j].x));
                acc[j].y = fmaf(y.x, tt.y, fmaf(y.y, tt.w, acc[j].y));
            }
        }
#pragma unroll
        for (int j = 0; j < 4; ++j) A1[(2+4*j)*65536 + row] = acc[j];
    } else if (g == 1) {                // ky = 57,61,65,69 : y1 = a - i b
        float2 acc[4] = {};
#pragma unroll 4
        for (int wp2 = 0; wp2 < 32; ++wp2) {
            float2 a = ydp02[wp2*65 + lane];
            float2 b = ydp13[wp2*65 + lane];
#pragma unroll
            for (int j = 0; j < 4; ++j) {
                float4 tt = *(const float4*)&twl[(1+4*j)*64 + 2*wp2];
                acc[j].x = fmaf(tt.x, a.x, fmaf( tt.y, b.x,
                           fmaf(tt.z, a.y, fmaf( tt.w, b.y, acc[j].x))));
                acc[j].y = fmaf(tt.y, a.x, fmaf(-tt.x, b.x,
                           fmaf(tt.w, a.y, fmaf(-tt.z, b.y, acc[j].y))));
            }
        }
#pragma unroll
        for (int j = 0; j < 4; ++j) A1[(1+4*j)*65536 + row] = acc[j];
    } else {                            // ky = 59,63,67,71 : y3 = a + i b
        float2 acc[4] = {};
#pragma unroll 4
        for (int wp2 = 0; wp2 < 32; ++wp2) {
            float2 a = ydp02[wp2*65 + lane];
            float2 b = ydp13[wp2*65 + lane];
#pragma unroll
            for (int j = 0; j < 4; ++j) {
                float4 tt = *(const float4*)&twl[(3+4*j)*64 + 2*wp2];
                acc[j].x = fmaf(tt.x, a.x, fmaf(-tt.y, b.x,
                           fmaf(tt.z, a.y, fmaf(-tt.w, b.y, acc[j].x))));
                acc[j].y = fmaf(tt.y, a.x, fmaf( tt.x, b.x,
                           fmaf(tt.w, a.y, fmaf( tt.z, b.y, acc[j].y))));
            }
        }
#pragma unroll
        for (int j = 0; j < 4; ++j) A1[(3+4*j)*65536 + row] = acc[j];
    }
}

// ============ K1 = wprep ∪ fwd_w (independent) ============
__global__ __launch_bounds__(256) void k1_kernel(
    const int* __restrict__ q_core, const int* __restrict__ q_f3,
    const float* __restrict__ core_scale, const float* __restrict__ core_min,
    const float* __restrict__ f_scales, const float* __restrict__ f_mins,
    float2* __restrict__ CL, const float* __restrict__ x,
    float2* __restrict__ A1)
{
    if (blockIdx.x < 272)
        wprep_body(blockIdx.x, q_core, q_f3, core_scale, core_min,
                   f_scales, f_mins, CL);
    else
        fwdw_body(blockIdx.x - 272, x, A1);
}

// ============ weights body: per-mode k/j/i contractions ============
__device__ __forceinline__ void weights_body(
    int m, const float2* __restrict__ CL, const int* __restrict__ q_f0,
    const int* __restrict__ q_f1, const int* __restrict__ q_f2,
    const float* __restrict__ f_scales, const float* __restrict__ f_mins,
    float2* __restrict__ W4)
{
    __shared__ float2 F0s[512], F1s[512];
    __shared__ float2 C2p[16*17];
    __shared__ float2 A2p[16*33];
    int t = threadIdx.x;
    int c = m / 17, d = m % 17;
    float s0 = f_scales[0], m0 = f_mins[0];
    float s1 = f_scales[1], m1 = f_mins[1];
    float s2 = f_scales[2], m2 = f_mins[2];

    for (int e = t; e < 512; e += 256) {
        F0s[e] = make_float2(q_f0[2*e]*s0 + m0, q_f0[2*e+1]*s0 + m0);
        F1s[e] = make_float2(q_f1[2*e]*s1 + m1, q_f1[2*e+1]*s1 + m1);
    }
    {   // phase 1: C2[i,j] = sum_k CL[d][k][ij] * F2[c,k]   (coalesced reads)
        float2 acc = make_float2(0.f, 0.f);
#pragma unroll
        for (int k = 0; k < 16; ++k) {
            float2 clv = CL[(d*16 + k)*256 + t];
            float2 f2 = make_float2(q_f2[(c*16+k)*2]*s2 + m2,
                                    q_f2[(c*16+k)*2+1]*s2 + m2);
            acc = cfma(clv, f2, acc);
        }
        __syncthreads();
        C2p[(t >> 4)*17 + (t & 15)] = acc;
    }
    __syncthreads();
#pragma unroll
    for (int r = 0; r < 2; ++r) {   // phase 2: A2[i,b] = sum_j C2[i,j]*F1[b,j]
        int e = t + r*256; int i = e & 15, b = e >> 4;
        float2 acc = make_float2(0.f, 0.f);
#pragma unroll
        for (int j = 0; j < 16; ++j)
            acc = cfma(C2p[i*17 + j], F1s[b*16 + j], acc);
        A2p[i*33 + b] = acc;
    }
    __syncthreads();
    {   // phase 3: W4[m,a,b] = sum_i F0[a,i]*A2[i,b]
        int b = t & 31, a0 = t >> 5;
#pragma unroll
        for (int q = 0; q < 4; ++q) {
            int a = a0 + 8*q;
            float2 acc = make_float2(0.f, 0.f);
#pragma unroll
            for (int i = 0; i < 16; ++i)
                acc = cfma(F0s[a*16 + i], A2p[i*33 + b], acc);
            W4[m*1024 + a*32 + b] = acc;
        }
    }
}

// ============ fwd_h body: partial DFT along h ============
__device__ __forceinline__ void fwdh_body(
    int bid, const float2* __restrict__ A1, float2* __restrict__ X)
{
    __shared__ float2 tbl[256];
    __shared__ float as_re[8*264];
    __shared__ float as_im[8*264];
    int tid = threadIdx.x;
    int ky = bid >> 5, bi0 = (bid & 31) * 8;
    tbl[tid] = make_float2(cospif(tid * (1.f/128.f)), -sinpif(tid * (1.f/128.f)));
    for (int idx = tid; idx < 2048; idx += 256) {
        int b = idx >> 8, h = idx & 255;
        float2 v = A1[ky*65536 + (bi0 + b)*256 + h];
        int ad = (h >> 5)*264 + (h & 31)*8 + b;
        as_re[ad] = v.x; as_im[ad] = v.y;
    }
    __syncthreads();
    int lane = tid & 63, g = tid >> 6;
    int bl = lane & 7, q = lane >> 3;
    int kx0 = g * 8;
    float2 acc[8];
#pragma unroll
    for (int j = 0; j < 8; ++j) acc[j] = make_float2(0.f, 0.f);
    int base = q*264 + bl;
    for (int hh = 0; hh < 32; ++hh) {
        float ar = as_re[base + hh*8];
        float ai = as_im[base + hh*8];
#pragma unroll
        for (int j = 0; j < 8; ++j) {
            int kk = kx0 + j + 112;
            float2 t = tbl[(kk * hh) & 255];      // wave-uniform broadcast
            acc[j].x = fmaf(ar, t.x, fmaf(-ai, t.y, acc[j].x));
            acc[j].y = fmaf(ar, t.y, fmaf( ai, t.x, acc[j].y));
        }
    }
    float2 fstep = tbl[q * 32];                   // e^{-2pi i q/8}
    float2 f = make_float2(1.f, 0.f);
#pragma unroll
    for (int j = 0; j < 8; ++j) {
        float2 v = cmul(acc[j], f);
        v.x += __shfl_xor(v.x, 8);  v.y += __shfl_xor(v.y, 8);
        v.x += __shfl_xor(v.x, 16); v.y += __shfl_xor(v.y, 16);
        v.x += __shfl_xor(v.x, 32); v.y += __shfl_xor(v.y, 32);
        acc[j] = v;
        f = cmul(f, fstep);
    }
    if (q == 0) {
        const float inv = 1.f / 65536.f;
#pragma unroll
        for (int j = 0; j < 8; ++j)
            X[((kx0 + j)*17 + ky)*256 + bi0 + bl] =
                make_float2(acc[j].x * inv, acc[j].y * inv);
    }
}

// ============ K2 = weights ∪ fwd_h (both depend only on K1) ============
__global__ __launch_bounds__(256) void k2_kernel(
    const float2* __restrict__ CL, const int* __restrict__ q_f0,
    const int* __restrict__ q_f1, const int* __restrict__ q_f2,
    const float* __restrict__ f_scales, const float* __restrict__ f_mins,
    float2* __restrict__ W4, const float2* __restrict__ A1,
    float2* __restrict__ X)
{
    if (blockIdx.x < 544)
        weights_body(blockIdx.x, CL, q_f0, q_f1, q_f2, f_scales, f_mins, W4);
    else
        fwdh_body(blockIdx.x - 544, A1, X);
}

// ================= per-mode channel mixing =================
__global__ __launch_bounds__(256) void mix_kernel(const float2* __restrict__ X,
                                                  const float2* __restrict__ W4,
                                                  float2* __restrict__ Mx)
{
    __shared__ float2 Xs[256];
    __shared__ float2 Ws[1024];
    int tid = threadIdx.x, mode = blockIdx.x;
    Xs[tid] = X[mode*256 + tid];
    for (int idx = tid; idx < 1024; idx += 256) Ws[idx] = W4[mode*1024 + idx];
    __syncthreads();
    int b = tid >> 5, o = tid & 31;
    float2 acc = make_float2(0.f, 0.f);
#pragma unroll
    for (int i = 0; i < 32; ++i)
        acc = cfma(Xs[b*32 + i], Ws[i*32 + o], acc);
    Mx[mode*256 + tid] = acc;
}

// ================= fused inverse, w-quadrant registers =================
template<int KY0, int NK>
__device__ __forceinline__ void invh_part(int h, int hh, const float2* ms, float2* Ts)
{
    float2 acc[NK];
#pragma unroll
    for (int j = 0; j < NK; ++j) acc[j] = make_float2(0.f, 0.f);
    int n0 = (112 * h) & 255;
    float tr = cospif(n0 * (1.f/128.f)), ti = sinpif(n0 * (1.f/128.f));
    float sr = cospif(h  * (1.f/128.f)), si = sinpif(h  * (1.f/128.f));
    for (int kx = 0; kx < 32; ++kx) {
#pragma unroll
        for (int j = 0; j < NK; ++j) {
            float2 mv = ms[kx*17 + KY0 + j];       // 2-way broadcast
            acc[j].x = fmaf(mv.x, tr, fmaf(-mv.y, ti, acc[j].x));
            acc[j].y = fmaf(mv.x, ti, fmaf( mv.y, tr, acc[j].y));
        }
        float ntr = fmaf(tr, sr, -ti*si);          // t *= step
        ti = fmaf(tr, si, ti*sr);
        tr = ntr;
    }
#pragma unroll
    for (int j = 0; j < NK; ++j) Ts[hh*18 + KY0 + j] = acc[j];
}

__global__ __launch_bounds__(256) void inv_kernel(const float2* __restrict__ Mx,
                                                  const int* __restrict__ q_bias,
                                                  const float* __restrict__ b_scale,
                                                  const float* __restrict__ b_min,
                                                  float* __restrict__ out)
{
    __shared__ float2 ms[544];
    __shared__ __align__(16) float2 Ts[32*18];     // rows padded to 18
    int tid = threadIdx.x;
    int bo = blockIdx.x & 255, hc = blockIdx.x >> 8;
    for (int idx = tid; idx < 544; idx += 256) ms[idx] = Mx[idx*256 + bo];
    __syncthreads();
    {   // phase 1: Ts[hh][ky] = sum_kx ms[kx][ky] e^{+2pi i (kx+112)h/256}
        int hh = tid & 31, g = tid >> 5;           // g in [0,8)
        int h = hc*32 + hh;
        if (g < 7) {
            switch (g) {
                case 0: invh_part<0, 2>(h, hh, ms, Ts); break;
                case 1: invh_part<2, 2>(h, hh, ms, Ts); break;
                case 2: invh_part<4, 2>(h, hh, ms, Ts); break;
                case 3: invh_part<6, 2>(h, hh, ms, Ts); break;
                case 4: invh_part<8, 2>(h, hh, ms, Ts); break;
                case 5: invh_part<10,2>(h, hh, ms, Ts); break;
                default:invh_part<12,2>(h, hh, ms, Ts); break;
            }
        } else {
            invh_part<14,3>(h, hh, ms, Ts);
        }
    }
    __syncthreads();
    {   // phase 2: out[h][w0+64q] = 2*Re(T[h]*e^{i th0}*i^{ky*q}) + bias
        int w0 = tid & 63, hs = tid >> 6;          // 4 h-subgroups of 8
        float C[17], S[17];
        {
            int n0 = (56 * w0) & 255;
            float tr = cospif(n0 * (1.f/128.f)), ti = sinpif(n0 * (1.f/128.f));
            float sr = cospif(w0 * (1.f/128.f)), si = sinpif(w0 * (1.f/128.f));
#pragma unroll
            for (int ky = 0; ky < 17; ++ky) {
                C[ky] = tr; S[ky] = ti;
                float ntr = fmaf(tr, sr, -ti*si);
                ti = fmaf(tr, si, ti*sr);
                tr = ntr;
            }
        }
        float bias = q_bias[bo & 31] * (*b_scale) + (*b_min);
        float* obase = out + (size_t)bo*65536 + (size_t)hc*32*256;

#pragma unroll
        for (int r = 0; r < 8; ++r) {
            int hh = hs*8 + r;
            const float4* tp = (const float4*)&Ts[hh*18];
            float R0 = 0.f, R1 = 0.f, R2 = 0.f, R3 = 0.f, I1 = 0.f, I3 = 0.f;
#pragma unroll
            for (int kp = 0; kp < 9; ++kp) {
                float vx0, vy0, vx1 = 0.f, vy1 = 0.f;
                if (kp < 8) {
                    float4 v4 = tp[kp];
                    vx0 = v4.x; vy0 = v4.y; vx1 = v4.z; vy1 = v4.w;
                } else {
                    float2 v2 = Ts[hh*18 + 16];
                    vx0 = v2.x; vy0 = v2.y;
                }
#pragma unroll
                for (int half = 0; half < 2; ++half) {
                    if (kp == 8 && half == 1) break;
                    const int ky = 2*kp + half;
                    float vx = half ? vx1 : vx0;
                    float vy = half ? vy1 : vy0;
                    float ur = fmaf(vx, C[ky], -vy*S[ky]);
                    if ((ky & 1) == 0) {
                        if ((ky & 3) == 0) R0 += ur; else R2 += ur;
                    } else {
                        float ui = fmaf(vx, S[ky], vy*C[ky]);
                        if ((ky & 3) == 1) { R1 += ur; I1 += ui; }
                        else               { R3 += ur; I3 += ui; }
                    }
                }
            }
            float e02 = R0 + R2, d02 = R0 - R2;
            float e13 = R1 + R3, di  = I3 - I1;
            float q0 = e02 + e13, q2 = e02 - e13;
            float q1 = d02 + di,  q3 = d02 - di;
            obase[hh*256 + w0]       = fmaf(2.f, q0, bias);
            obase[hh*256 + w0 + 64]  = fmaf(2.f, q1, bias);
            obase[hh*256 + w0 + 128] = fmaf(2.f, q2, bias);
            obase[hh*256 + w0 + 192] = fmaf(2.f, q3, bias);
        }
    }
}

extern "C" void kernel_launch(void* const* d_in, const int* in_sizes, int n_in,
                              void* d_out, int out_size, void* d_ws, size_t ws_size,
                              hipStream_t stream) {
    const float* x          = (const float*)d_in[0];
    const float* core_scale = (const float*)d_in[1];
    const float* core_min   = (const float*)d_in[2];
    const float* f_scales   = (const float*)d_in[3];
    const float* f_mins     = (const float*)d_in[4];
    const float* b_scale    = (const float*)d_in[5];
    const float* b_min      = (const float*)d_in[6];
    const int* q_core = (const int*)d_in[7];
    const int* q_f0   = (const int*)d_in[8];
    const int* q_f1   = (const int*)d_in[9];
    const int* q_f2   = (const int*)d_in[10];
    const int* q_f3   = (const int*)d_in[11];
    const int* q_bias = (const int*)d_in[12];
    float* out = (float*)d_out;

    float2* ws = (float2*)d_ws;
    float2* A1 = ws;                 // 1,114,112  [17][256 bi][256 h]
    float2* W4 = ws + 1114112;       //   557,056  [544][32][32]
    float2* X  = W4 + 557056;        //   139,264  [544][256]
    float2* Mx = X + 139264;         //   139,264  [544][256]
    float2* CL = Mx + 139264;        //    69,632  [17][16][256]
    (void)ws_size; (void)n_in; (void)in_sizes; (void)out_size;

    k1_kernel<<<1296, 256, 0, stream>>>(q_core, q_f3, core_scale, core_min,
                                        f_scales, f_mins, CL, x, A1);
    k2_kernel<<<1088, 256, 0, stream>>>(CL, q_f0, q_f1, q_f2,
                                        f_scales, f_mins, W4, A1, X);
    mix_kernel<<<544, 256, 0, stream>>>(X, W4, Mx);
    inv_kernel<<<2048, 256, 0, stream>>>(Mx, q_bias, b_scale, b_min, out);
}

// Round 10
// 180.145 us; speedup vs baseline: 1.1446x; 1.0336x over previous
//
#include <hip/hip_runtime.h>

// QuantizedSpectralConv on MI355X (gfx950).
// x [8,32,256,256] f32; Tucker: core[16,16,16,9] F0[32,16] F1[32,16] F2[32,16]
// F3[17,9] complex, deq = q*scale+min. Active window: kx in [112,144),
// ky in [56,73) of the (256,129) rfft2. norm="forward" (1/65536 on fwd).
//
// Dispatch plan (horizontal fusion of independent stages, 4 launches):
//   K1 = wprep(272) ∪ fwd_w(1024)   -- independent chains
//   K2 = weights(544) ∪ fwd_h(544)  -- each depends only on K1
//   K3 = mix(544); K4 = inv(2048)
// Workspace (float2):
//   A1 [17 ky][256 bi][256 h]; X [544 mode][256 bi]; W4 [544][32][32];
//   Mx [544 mode][256 bo];     CL [17 d][16 k][256 ij]
// LDS rule: addresses wave-uniform (broadcast) or lane-consecutive only.

__device__ __forceinline__ float2 cfma(float2 a, float2 b, float2 c) {
    c.x = fmaf(a.x, b.x, fmaf(-a.y, b.y, c.x));
    c.y = fmaf(a.x, b.y, fmaf(a.y, b.x, c.y));
    return c;
}
__device__ __forceinline__ float2 cmul(float2 a, float2 b) {
    return make_float2(a.x*b.x - a.y*b.y, a.x*b.y + a.y*b.x);
}

// ============ wprep body: CL[d][k][ij] = sum_l core[ij,k,l] * F3[d,l] ========
__device__ __forceinline__ void wprep_body(
    int bid, const int* __restrict__ q_core, const int* __restrict__ q_f3,
    const float* __restrict__ core_scale, const float* __restrict__ core_min,
    const float* __restrict__ f_scales, const float* __restrict__ f_mins,
    float2* __restrict__ CL)
{
    int d = bid >> 4, k = bid & 15;
    int ij = threadIdx.x;
    float cs = *core_scale, cm = *core_min;
    float s3 = f_scales[3], m3 = f_mins[3];
    const int* qc = q_core + ((ij*16 + k)*9)*2;
    float2 acc = make_float2(0.f, 0.f);
#pragma unroll
    for (int l = 0; l < 9; ++l) {
        int2 q = *(const int2*)(qc + l*2);
        float2 ce = make_float2(q.x*cs + cm, q.y*cs + cm);
        float2 f3 = make_float2(q_f3[(d*9+l)*2]*s3 + m3, q_f3[(d*9+l)*2+1]*s3 + m3);
        acc = cfma(ce, f3, acc);
    }
    CL[(d*16 + k)*256 + ij] = acc;
}

// ================= fwd_w body: partial DFT along w =================
// Quadrant pre-combine; LDS ops paired over w' (b64 y-pairs, b128 twiddles).
__device__ __forceinline__ void fwdw_body(
    int bid, const float* __restrict__ x, float2* __restrict__ A1)
{
    __shared__ float2 ysp0[32*65], ysp2[32*65], ydp02[32*65], ydp13[32*65];
    __shared__ __align__(16) float2 twl[17*64];   // [ki][w'], ki = ky-56
    int tid = threadIdx.x;
    int row0 = bid * 64;

    for (int i = tid; i < 17*64; i += 256) {
        int ki = i >> 6, wp = i & 63;
        int n = ((56 + ki) * wp) & 255;
        float a = n * (1.f/128.f);
        twl[i] = make_float2(cospif(a), -sinpif(a));
    }
    const float2* xf2 = (const float2*)x;
    for (int i2 = tid; i2 < 2048; i2 += 256) {
        int r = i2 >> 5, w2 = i2 & 31;  // row, wp-pair index
        const float2* xb = xf2 + (size_t)(row0 + r) * 128 + w2;
        float2 a0 = xb[0], a1 = xb[32], a2 = xb[64], a3 = xb[96];
        int ad = w2*65 + r;             // [wp2][row], row-consecutive
        float s02a = a0.x + a2.x, s13a = a1.x + a3.x;
        float s02b = a0.y + a2.y, s13b = a1.y + a3.y;
        ysp0[ad]  = make_float2(s02a + s13a, s02b + s13b);
        ysp2[ad]  = make_float2(s02a - s13a, s02b - s13b);
        ydp02[ad] = make_float2(a0.x - a2.x, a0.y - a2.y);
        ydp13[ad] = make_float2(a1.x - a3.x, a1.y - a3.y);
    }
    __syncthreads();

    int lane = tid & 63, g = tid >> 6;  // wave g owns residue class g
    int row = row0 + lane;
    if (g == 0) {                       // ky = 56,60,64,68,72 : real y0
        float2 acc[5] = {};
#pragma unroll 4
        for (int wp2 = 0; wp2 < 32; ++wp2) {
            float2 y = ysp0[wp2*65 + lane];
#pragma unroll
            for (int j = 0; j < 5; ++j) {
                float4 tt = *(const float4*)&twl[(4*j)*64 + 2*wp2];
                acc[j].x = fmaf(y.x, tt.x, fmaf(y.y, tt.z, acc[j].x));
                acc[j].y = fmaf(y.x, tt.y, fmaf(y.y, tt.w, acc[j].y));
            }
        }
#pragma unroll
        for (int j = 0; j < 5; ++j) A1[(4*j)*65536 + row] = acc[j];
    } else if (g == 2) {                // ky = 58,62,66,70 : real y2
        float2 acc[4] = {};
#pragma unroll 4
        for (int wp2 = 0; wp2 < 32; ++wp2) {
            float2 y = ysp2[wp2*65 + lane];
#pragma unroll
            for (int j = 0; j < 4; ++j) {
                float4 tt = *(const float4*)&twl[(2+4*j)*64 + 2*wp2];
                acc[j].x = fmaf(y.x, tt.x, fmaf(y.y, tt.z, acc[j].x));
                acc[j].y = fmaf(y.x, tt.y, fmaf(y.y, tt.w, acc[j].y));
            }
        }
#pragma unroll
        for (int j = 0; j < 4; ++j) A1[(2+4*j)*65536 + row] = acc[j];
    } else if (g == 1) {                // ky = 57,61,65,69 : y1 = a - i b
        float2 acc[4] = {};
#pragma unroll 4
        for (int wp2 = 0; wp2 < 32; ++wp2) {
            float2 a = ydp02[wp2*65 + lane];
            float2 b = ydp13[wp2*65 + lane];
#pragma unroll
            for (int j = 0; j < 4; ++j) {
                float4 tt = *(const float4*)&twl[(1+4*j)*64 + 2*wp2];
                acc[j].x = fmaf(tt.x, a.x, fmaf( tt.y, b.x,
                           fmaf(tt.z, a.y, fmaf( tt.w, b.y, acc[j].x))));
                acc[j].y = fmaf(tt.y, a.x, fmaf(-tt.x, b.x,
                           fmaf(tt.w, a.y, fmaf(-tt.z, b.y, acc[j].y))));
            }
        }
#pragma unroll
        for (int j = 0; j < 4; ++j) A1[(1+4*j)*65536 + row] = acc[j];
    } else {                            // ky = 59,63,67,71 : y3 = a + i b
        float2 acc[4] = {};
#pragma unroll 4
        for (int wp2 = 0; wp2 < 32; ++wp2) {
            float2 a = ydp02[wp2*65 + lane];
            float2 b = ydp13[wp2*65 + lane];
#pragma unroll
            for (int j = 0; j < 4; ++j) {
                float4 tt = *(const float4*)&twl[(3+4*j)*64 + 2*wp2];
                acc[j].x = fmaf(tt.x, a.x, fmaf(-tt.y, b.x,
                           fmaf(tt.z, a.y, fmaf(-tt.w, b.y, acc[j].x))));
                acc[j].y = fmaf(tt.y, a.x, fmaf( tt.x, b.x,
                           fmaf(tt.w, a.y, fmaf( tt.z, b.y, acc[j].y))));
            }
        }
#pragma unroll
        for (int j = 0; j < 4; ++j) A1[(3+4*j)*65536 + row] = acc[j];
    }
}

// ============ K1 = wprep ∪ fwd_w (independent) ============
__global__ __launch_bounds__(256) void k1_kernel(
    const int* __restrict__ q_core, const int* __restrict__ q_f3,
    const float* __restrict__ core_scale, const float* __restrict__ core_min,
    const float* __restrict__ f_scales, const float* __restrict__ f_mins,
    float2* __restrict__ CL, const float* __restrict__ x,
    float2* __restrict__ A1)
{
    if (blockIdx.x < 272)
        wprep_body(blockIdx.x, q_core, q_f3, core_scale, core_min,
                   f_scales, f_mins, CL);
    else
        fwdw_body(blockIdx.x - 272, x, A1);
}

// ============ weights body: per-mode k/j/i contractions ============
__device__ __forceinline__ void weights_body(
    int m, const float2* __restrict__ CL, const int* __restrict__ q_f0,
    const int* __restrict__ q_f1, const int* __restrict__ q_f2,
    const float* __restrict__ f_scales, const float* __restrict__ f_mins,
    float2* __restrict__ W4)
{
    __shared__ float2 F0s[512], F1s[512];
    __shared__ float2 C2p[16*17];
    __shared__ float2 A2p[16*33];
    int t = threadIdx.x;
    int c = m / 17, d = m % 17;
    float s0 = f_scales[0], m0 = f_mins[0];
    float s1 = f_scales[1], m1 = f_mins[1];
    float s2 = f_scales[2], m2 = f_mins[2];

    for (int e = t; e < 512; e += 256) {
        F0s[e] = make_float2(q_f0[2*e]*s0 + m0, q_f0[2*e+1]*s0 + m0);
        F1s[e] = make_float2(q_f1[2*e]*s1 + m1, q_f1[2*e+1]*s1 + m1);
    }
    {   // phase 1: C2[i,j] = sum_k CL[d][k][ij] * F2[c,k]   (coalesced reads)
        float2 acc = make_float2(0.f, 0.f);
#pragma unroll
        for (int k = 0; k < 16; ++k) {
            float2 clv = CL[(d*16 + k)*256 + t];
            float2 f2 = make_float2(q_f2[(c*16+k)*2]*s2 + m2,
                                    q_f2[(c*16+k)*2+1]*s2 + m2);
            acc = cfma(clv, f2, acc);
        }
        __syncthreads();
        C2p[(t >> 4)*17 + (t & 15)] = acc;
    }
    __syncthreads();
#pragma unroll
    for (int r = 0; r < 2; ++r) {   // phase 2: A2[i,b] = sum_j C2[i,j]*F1[b,j]
        int e = t + r*256; int i = e & 15, b = e >> 4;
        float2 acc = make_float2(0.f, 0.f);
#pragma unroll
        for (int j = 0; j < 16; ++j)
            acc = cfma(C2p[i*17 + j], F1s[b*16 + j], acc);
        A2p[i*33 + b] = acc;
    }
    __syncthreads();
    {   // phase 3: W4[m,a,b] = sum_i F0[a,i]*A2[i,b]
        int b = t & 31, a0 = t >> 5;
#pragma unroll
        for (int q = 0; q < 4; ++q) {
            int a = a0 + 8*q;
            float2 acc = make_float2(0.f, 0.f);
#pragma unroll
            for (int i = 0; i < 16; ++i)
                acc = cfma(F0s[a*16 + i], A2p[i*33 + b], acc);
            W4[m*1024 + a*32 + b] = acc;
        }
    }
}

// ============ fwd_h body: partial DFT along h ============
__device__ __forceinline__ void fwdh_body(
    int bid, const float2* __restrict__ A1, float2* __restrict__ X)
{
    __shared__ float2 tbl[256];
    __shared__ float as_re[8*264];
    __shared__ float as_im[8*264];
    int tid = threadIdx.x;
    int ky = bid >> 5, bi0 = (bid & 31) * 8;
    tbl[tid] = make_float2(cospif(tid * (1.f/128.f)), -sinpif(tid * (1.f/128.f)));
    for (int idx = tid; idx < 2048; idx += 256) {
        int b = idx >> 8, h = idx & 255;
        float2 v = A1[ky*65536 + (bi0 + b)*256 + h];
        int ad = (h >> 5)*264 + (h & 31)*8 + b;
        as_re[ad] = v.x; as_im[ad] = v.y;
    }
    __syncthreads();
    int lane = tid & 63, g = tid >> 6;
    int bl = lane & 7, q = lane >> 3;
    int kx0 = g * 8;
    float2 acc[8];
#pragma unroll
    for (int j = 0; j < 8; ++j) acc[j] = make_float2(0.f, 0.f);
    int base = q*264 + bl;
    for (int hh = 0; hh < 32; ++hh) {
        float ar = as_re[base + hh*8];
        float ai = as_im[base + hh*8];
#pragma unroll
        for (int j = 0; j < 8; ++j) {
            int kk = kx0 + j + 112;
            float2 t = tbl[(kk * hh) & 255];      // wave-uniform broadcast
            acc[j].x = fmaf(ar, t.x, fmaf(-ai, t.y, acc[j].x));
            acc[j].y = fmaf(ar, t.y, fmaf( ai, t.x, acc[j].y));
        }
    }
    float2 fstep = tbl[q * 32];                   // e^{-2pi i q/8}
    float2 f = make_float2(1.f, 0.f);
#pragma unroll
    for (int j = 0; j < 8; ++j) {
        float2 v = cmul(acc[j], f);
        v.x += __shfl_xor(v.x, 8);  v.y += __shfl_xor(v.y, 8);
        v.x += __shfl_xor(v.x, 16); v.y += __shfl_xor(v.y, 16);
        v.x += __shfl_xor(v.x, 32); v.y += __shfl_xor(v.y, 32);
        acc[j] = v;
        f = cmul(f, fstep);
    }
    if (q == 0) {
        const float inv = 1.f / 65536.f;
#pragma unroll
        for (int j = 0; j < 8; ++j)
            X[((kx0 + j)*17 + ky)*256 + bi0 + bl] =
                make_float2(acc[j].x * inv, acc[j].y * inv);
    }
}

// ============ K2 = weights ∪ fwd_h (both depend only on K1) ============
__global__ __launch_bounds__(256) void k2_kernel(
    const float2* __restrict__ CL, const int* __restrict__ q_f0,
    const int* __restrict__ q_f1, const int* __restrict__ q_f2,
    const float* __restrict__ f_scales, const float* __restrict__ f_mins,
    float2* __restrict__ W4, const float2* __restrict__ A1,
    float2* __restrict__ X)
{
    if (blockIdx.x < 544)
        weights_body(blockIdx.x, CL, q_f0, q_f1, q_f2, f_scales, f_mins, W4);
    else
        fwdh_body(blockIdx.x - 544, A1, X);
}

// ================= per-mode channel mixing =================
__global__ __launch_bounds__(256) void mix_kernel(const float2* __restrict__ X,
                                                  const float2* __restrict__ W4,
                                                  float2* __restrict__ Mx)
{
    __shared__ float2 Xs[256];
    __shared__ float2 Ws[1024];
    int tid = threadIdx.x, mode = blockIdx.x;
    Xs[tid] = X[mode*256 + tid];
    for (int idx = tid; idx < 1024; idx += 256) Ws[idx] = W4[mode*1024 + idx];
    __syncthreads();
    int b = tid >> 5, o = tid & 31;
    float2 acc = make_float2(0.f, 0.f);
#pragma unroll
    for (int i = 0; i < 32; ++i)
        acc = cfma(Xs[b*32 + i], Ws[i*32 + o], acc);
    Mx[mode*256 + tid] = acc;
}

// ================= fused inverse =================
// Grid 2048 = bo(256) x hc(8); block covers 32 h x 256 w.
// Phase 1: wave-uniform runtime-ky assignment -- a wave's two 32-lane halves
// handle different ky via ks=lane>>5, SAME code path (no EXEC-masked double
// execution of templated bodies; the old g=tid>>5 switch made every wave run
// two bodies serially). ms reads are 2-address half-wave broadcasts (free).
__global__ __launch_bounds__(256) void inv_kernel(const float2* __restrict__ Mx,
                                                  const int* __restrict__ q_bias,
                                                  const float* __restrict__ b_scale,
                                                  const float* __restrict__ b_min,
                                                  float* __restrict__ out)
{
    __shared__ float2 ms[544];
    __shared__ __align__(16) float2 Ts[32*18];     // rows padded to 18
    int tid = threadIdx.x;
    int bo = blockIdx.x & 255, hc = blockIdx.x >> 8;
    for (int idx = tid; idx < 544; idx += 256) ms[idx] = Mx[idx*256 + bo];
    __syncthreads();
    {   // phase 1: Ts[hh][ky] = sum_kx ms[kx][ky] e^{+2pi i (kx+112)h/256}
        int lane = tid & 63, w = tid >> 6;         // wave id
        int hh = lane & 31, ks = lane >> 5;        // ky slot 0/1
        int h = hc*32 + hh;
        int n0 = (112 * h) & 255;
        float tr = cospif(n0 * (1.f/128.f)), ti = sinpif(n0 * (1.f/128.f));
        float sr = cospif(h  * (1.f/128.f)), si = sinpif(h  * (1.f/128.f));
        if (w < 3) {                               // ky = 4w+ks, 4w+ks+2
            int ky0 = 4*w + ks;
            float2 a0 = make_float2(0.f,0.f), a1 = make_float2(0.f,0.f);
            for (int kx = 0; kx < 32; ++kx) {
                const float2* mr = ms + kx*17;
                float2 v0 = mr[ky0], v1 = mr[ky0+2];
                a0.x = fmaf(v0.x, tr, fmaf(-v0.y, ti, a0.x));
                a0.y = fmaf(v0.x, ti, fmaf( v0.y, tr, a0.y));
                a1.x = fmaf(v1.x, tr, fmaf(-v1.y, ti, a1.x));
                a1.y = fmaf(v1.x, ti, fmaf( v1.y, tr, a1.y));
                float ntr = fmaf(tr, sr, -ti*si);
                ti = fmaf(tr, si, ti*sr);
                tr = ntr;
            }
            Ts[hh*18 + ky0]     = a0;
            Ts[hh*18 + ky0 + 2] = a1;
        } else {                                   // ky = 12+ks, 14+ks, (16)
            int ky0 = 12 + ks;
            int ky2 = ky0 + 4, ky2c = ky2 > 16 ? 16 : ky2;
            float2 a0 = make_float2(0.f,0.f), a1 = make_float2(0.f,0.f),
                   a2 = make_float2(0.f,0.f);
            for (int kx = 0; kx < 32; ++kx) {
                const float2* mr = ms + kx*17;
                float2 v0 = mr[ky0], v1 = mr[ky0+2], v2 = mr[ky2c];
                a0.x = fmaf(v0.x, tr, fmaf(-v0.y, ti, a0.x));
                a0.y = fmaf(v0.x, ti, fmaf( v0.y, tr, a0.y));
                a1.x = fmaf(v1.x, tr, fmaf(-v1.y, ti, a1.x));
                a1.y = fmaf(v1.x, ti, fmaf( v1.y, tr, a1.y));
                a2.x = fmaf(v2.x, tr, fmaf(-v2.y, ti, a2.x));
                a2.y = fmaf(v2.x, ti, fmaf( v2.y, tr, a2.y));
                float ntr = fmaf(tr, sr, -ti*si);
                ti = fmaf(tr, si, ti*sr);
                tr = ntr;
            }
            Ts[hh*18 + ky0]     = a0;
            Ts[hh*18 + ky0 + 2] = a1;
            if (ky2 < 17) Ts[hh*18 + ky2] = a2;
        }
    }
    __syncthreads();
    {   // phase 2: out[h][w0+64q] = 2*Re(T[h]*e^{i th0}*i^{ky*q}) + bias
        int w0 = tid & 63, hs = tid >> 6;          // 4 h-subgroups of 8
        float C[17], S[17];
        {
            int n0 = (56 * w0) & 255;
            float tr = cospif(n0 * (1.f/128.f)), ti = sinpif(n0 * (1.f/128.f));
            float sr = cospif(w0 * (1.f/128.f)), si = sinpif(w0 * (1.f/128.f));
#pragma unroll
            for (int ky = 0; ky < 17; ++ky) {
                C[ky] = tr; S[ky] = ti;
                float ntr = fmaf(tr, sr, -ti*si);
                ti = fmaf(tr, si, ti*sr);
                tr = ntr;
            }
        }
        float bias = q_bias[bo & 31] * (*b_scale) + (*b_min);
        float* obase = out + (size_t)bo*65536 + (size_t)hc*32*256;

#pragma unroll
        for (int r = 0; r < 8; ++r) {
            int hh = hs*8 + r;
            const float4* tp = (const float4*)&Ts[hh*18];
            float R0 = 0.f, R1 = 0.f, R2 = 0.f, R3 = 0.f, I1 = 0.f, I3 = 0.f;
#pragma unroll
            for (int kp = 0; kp < 9; ++kp) {
                float vx0, vy0, vx1 = 0.f, vy1 = 0.f;
                if (kp < 8) {
                    float4 v4 = tp[kp];
                    vx0 = v4.x; vy0 = v4.y; vx1 = v4.z; vy1 = v4.w;
                } else {
                    float2 v2 = Ts[hh*18 + 16];
                    vx0 = v2.x; vy0 = v2.y;
                }
#pragma unroll
                for (int half = 0; half < 2; ++half) {
                    if (kp == 8 && half == 1) break;
                    const int ky = 2*kp + half;
                    float vx = half ? vx1 : vx0;
                    float vy = half ? vy1 : vy0;
                    float ur = fmaf(vx, C[ky], -vy*S[ky]);
                    if ((ky & 1) == 0) {
                        if ((ky & 3) == 0) R0 += ur; else R2 += ur;
                    } else {
                        float ui = fmaf(vx, S[ky], vy*C[ky]);
                        if ((ky & 3) == 1) { R1 += ur; I1 += ui; }
                        else               { R3 += ur; I3 += ui; }
                    }
                }
            }
            float e02 = R0 + R2, d02 = R0 - R2;
            float e13 = R1 + R3, di  = I3 - I1;
            float q0 = e02 + e13, q2 = e02 - e13;
            float q1 = d02 + di,  q3 = d02 - di;
            obase[hh*256 + w0]       = fmaf(2.f, q0, bias);
            obase[hh*256 + w0 + 64]  = fmaf(2.f, q1, bias);
            obase[hh*256 + w0 + 128] = fmaf(2.f, q2, bias);
            obase[hh*256 + w0 + 192] = fmaf(2.f, q3, bias);
        }
    }
}

extern "C" void kernel_launch(void* const* d_in, const int* in_sizes, int n_in,
                              void* d_out, int out_size, void* d_ws, size_t ws_size,
                              hipStream_t stream) {
    const float* x          = (const float*)d_in[0];
    const float* core_scale = (const float*)d_in[1];
    const float* core_min   = (const float*)d_in[2];
    const float* f_scales   = (const float*)d_in[3];
    const float* f_mins     = (const float*)d_in[4];
    const float* b_scale    = (const float*)d_in[5];
    const float* b_min      = (const float*)d_in[6];
    const int* q_core = (const int*)d_in[7];
    const int* q_f0   = (const int*)d_in[8];
    const int* q_f1   = (const int*)d_in[9];
    const int* q_f2   = (const int*)d_in[10];
    const int* q_f3   = (const int*)d_in[11];
    const int* q_bias = (const int*)d_in[12];
    float* out = (float*)d_out;

    float2* ws = (float2*)d_ws;
    float2* A1 = ws;                 // 1,114,112  [17][256 bi][256 h]
    float2* W4 = ws + 1114112;       //   557,056  [544][32][32]
    float2* X  = W4 + 557056;        //   139,264  [544][256]
    float2* Mx = X + 139264;         //   139,264  [544][256]
    float2* CL = Mx + 139264;        //    69,632  [17][16][256]
    (void)ws_size; (void)n_in; (void)in_sizes; (void)out_size;

    k1_kernel<<<1296, 256, 0, stream>>>(q_core, q_f3, core_scale, core_min,
                                        f_scales, f_mins, CL, x, A1);
    k2_kernel<<<1088, 256, 0, stream>>>(CL, q_f0, q_f1, q_f2,
                                        f_scales, f_mins, W4, A1, X);
    mix_kernel<<<544, 256, 0, stream>>>(X, W4, Mx);
    inv_kernel<<<2048, 256, 0, stream>>>(Mx, q_bias, b_scale, b_min, out);
}

// Round 11
// 178.279 us; speedup vs baseline: 1.1565x; 1.0105x over previous
//
#include <hip/hip_runtime.h>

// QuantizedSpectralConv on MI355X (gfx950).
// x [8,32,256,256] f32; Tucker: core[16,16,16,9] F0[32,16] F1[32,16] F2[32,16]
// F3[17,9] complex, deq = q*scale+min. Active window: kx in [112,144),
// ky in [56,73) of the (256,129) rfft2. norm="forward" (1/65536 on fwd).
//
// Dispatch plan (4 launches):
//   K1 = wprep(272) ∪ fwd_w(1024); K2 = weights(544) ∪ fwd_h(544);
//   K3 = mix(544); K4 = inv(1024 x 512thr, bo-major, 2 hc-chunks/block)
// Workspace (float2):
//   A1 [17 ky][256 bi][256 h]; X [544 mode][256 bi]; W4 [544][32][32];
//   Mx [544 mode][256 bo];     CL [17 d][16 k][256 ij]
// LDS rule: addresses wave-uniform (broadcast) or lane-consecutive only.

__device__ __forceinline__ float2 cfma(float2 a, float2 b, float2 c) {
    c.x = fmaf(a.x, b.x, fmaf(-a.y, b.y, c.x));
    c.y = fmaf(a.x, b.y, fmaf(a.y, b.x, c.y));
    return c;
}
__device__ __forceinline__ float2 cmul(float2 a, float2 b) {
    return make_float2(a.x*b.x - a.y*b.y, a.x*b.y + a.y*b.x);
}

// ============ wprep body: CL[d][k][ij] = sum_l core[ij,k,l] * F3[d,l] ========
__device__ __forceinline__ void wprep_body(
    int bid, const int* __restrict__ q_core, const int* __restrict__ q_f3,
    const float* __restrict__ core_scale, const float* __restrict__ core_min,
    const float* __restrict__ f_scales, const float* __restrict__ f_mins,
    float2* __restrict__ CL)
{
    int d = bid >> 4, k = bid & 15;
    int ij = threadIdx.x;
    float cs = *core_scale, cm = *core_min;
    float s3 = f_scales[3], m3 = f_mins[3];
    const int* qc = q_core + ((ij*16 + k)*9)*2;
    float2 acc = make_float2(0.f, 0.f);
#pragma unroll
    for (int l = 0; l < 9; ++l) {
        int2 q = *(const int2*)(qc + l*2);
        float2 ce = make_float2(q.x*cs + cm, q.y*cs + cm);
        float2 f3 = make_float2(q_f3[(d*9+l)*2]*s3 + m3, q_f3[(d*9+l)*2+1]*s3 + m3);
        acc = cfma(ce, f3, acc);
    }
    CL[(d*16 + k)*256 + ij] = acc;
}

// ================= fwd_w body: partial DFT along w =================
// Quadrant pre-combine; LDS ops paired over w' (b64 y-pairs, b128 twiddles).
__device__ __forceinline__ void fwdw_body(
    int bid, const float* __restrict__ x, float2* __restrict__ A1)
{
    __shared__ float2 ysp0[32*65], ysp2[32*65], ydp02[32*65], ydp13[32*65];
    __shared__ __align__(16) float2 twl[17*64];   // [ki][w'], ki = ky-56
    int tid = threadIdx.x;
    int row0 = bid * 64;

    for (int i = tid; i < 17*64; i += 256) {
        int ki = i >> 6, wp = i & 63;
        int n = ((56 + ki) * wp) & 255;
        float a = n * (1.f/128.f);
        twl[i] = make_float2(cospif(a), -sinpif(a));
    }
    const float2* xf2 = (const float2*)x;
    for (int i2 = tid; i2 < 2048; i2 += 256) {
        int r = i2 >> 5, w2 = i2 & 31;  // row, wp-pair index
        const float2* xb = xf2 + (size_t)(row0 + r) * 128 + w2;
        float2 a0 = xb[0], a1 = xb[32], a2 = xb[64], a3 = xb[96];
        int ad = w2*65 + r;             // [wp2][row], row-consecutive
        float s02a = a0.x + a2.x, s13a = a1.x + a3.x;
        float s02b = a0.y + a2.y, s13b = a1.y + a3.y;
        ysp0[ad]  = make_float2(s02a + s13a, s02b + s13b);
        ysp2[ad]  = make_float2(s02a - s13a, s02b - s13b);
        ydp02[ad] = make_float2(a0.x - a2.x, a0.y - a2.y);
        ydp13[ad] = make_float2(a1.x - a3.x, a1.y - a3.y);
    }
    __syncthreads();

    int lane = tid & 63, g = tid >> 6;  // wave g owns residue class g
    int row = row0 + lane;
    if (g == 0) {                       // ky = 56,60,64,68,72 : real y0
        float2 acc[5] = {};
#pragma unroll 4
        for (int wp2 = 0; wp2 < 32; ++wp2) {
            float2 y = ysp0[wp2*65 + lane];
#pragma unroll
            for (int j = 0; j < 5; ++j) {
                float4 tt = *(const float4*)&twl[(4*j)*64 + 2*wp2];
                acc[j].x = fmaf(y.x, tt.x, fmaf(y.y, tt.z, acc[j].x));
                acc[j].y = fmaf(y.x, tt.y, fmaf(y.y, tt.w, acc[j].y));
            }
        }
#pragma unroll
        for (int j = 0; j < 5; ++j) A1[(4*j)*65536 + row] = acc[j];
    } else if (g == 2) {                // ky = 58,62,66,70 : real y2
        float2 acc[4] = {};
#pragma unroll 4
        for (int wp2 = 0; wp2 < 32; ++wp2) {
            float2 y = ysp2[wp2*65 + lane];
#pragma unroll
            for (int j = 0; j < 4; ++j) {
                float4 tt = *(const float4*)&twl[(2+4*j)*64 + 2*wp2];
                acc[j].x = fmaf(y.x, tt.x, fmaf(y.y, tt.z, acc[j].x));
                acc[j].y = fmaf(y.x, tt.y, fmaf(y.y, tt.w, acc[j].y));
            }
        }
#pragma unroll
        for (int j = 0; j < 4; ++j) A1[(2+4*j)*65536 + row] = acc[j];
    } else if (g == 1) {                // ky = 57,61,65,69 : y1 = a - i b
        float2 acc[4] = {};
#pragma unroll 4
        for (int wp2 = 0; wp2 < 32; ++wp2) {
            float2 a = ydp02[wp2*65 + lane];
            float2 b = ydp13[wp2*65 + lane];
#pragma unroll
            for (int j = 0; j < 4; ++j) {
                float4 tt = *(const float4*)&twl[(1+4*j)*64 + 2*wp2];
                acc[j].x = fmaf(tt.x, a.x, fmaf( tt.y, b.x,
                           fmaf(tt.z, a.y, fmaf( tt.w, b.y, acc[j].x))));
                acc[j].y = fmaf(tt.y, a.x, fmaf(-tt.x, b.x,
                           fmaf(tt.w, a.y, fmaf(-tt.z, b.y, acc[j].y))));
            }
        }
#pragma unroll
        for (int j = 0; j < 4; ++j) A1[(1+4*j)*65536 + row] = acc[j];
    } else {                            // ky = 59,63,67,71 : y3 = a + i b
        float2 acc[4] = {};
#pragma unroll 4
        for (int wp2 = 0; wp2 < 32; ++wp2) {
            float2 a = ydp02[wp2*65 + lane];
            float2 b = ydp13[wp2*65 + lane];
#pragma unroll
            for (int j = 0; j < 4; ++j) {
                float4 tt = *(const float4*)&twl[(3+4*j)*64 + 2*wp2];
                acc[j].x = fmaf(tt.x, a.x, fmaf(-tt.y, b.x,
                           fmaf(tt.z, a.y, fmaf(-tt.w, b.y, acc[j].x))));
                acc[j].y = fmaf(tt.y, a.x, fmaf( tt.x, b.x,
                           fmaf(tt.w, a.y, fmaf( tt.z, b.y, acc[j].y))));
            }
        }
#pragma unroll
        for (int j = 0; j < 4; ++j) A1[(3+4*j)*65536 + row] = acc[j];
    }
}

// ============ K1 = wprep ∪ fwd_w (independent) ============
__global__ __launch_bounds__(256) void k1_kernel(
    const int* __restrict__ q_core, const int* __restrict__ q_f3,
    const float* __restrict__ core_scale, const float* __restrict__ core_min,
    const float* __restrict__ f_scales, const float* __restrict__ f_mins,
    float2* __restrict__ CL, const float* __restrict__ x,
    float2* __restrict__ A1)
{
    if (blockIdx.x < 272)
        wprep_body(blockIdx.x, q_core, q_f3, core_scale, core_min,
                   f_scales, f_mins, CL);
    else
        fwdw_body(blockIdx.x - 272, x, A1);
}

// ============ weights body: per-mode k/j/i contractions ============
__device__ __forceinline__ void weights_body(
    int m, const float2* __restrict__ CL, const int* __restrict__ q_f0,
    const int* __restrict__ q_f1, const int* __restrict__ q_f2,
    const float* __restrict__ f_scales, const float* __restrict__ f_mins,
    float2* __restrict__ W4)
{
    __shared__ float2 F0s[512], F1s[512];
    __shared__ float2 C2p[16*17];
    __shared__ float2 A2p[16*33];
    int t = threadIdx.x;
    int c = m / 17, d = m % 17;
    float s0 = f_scales[0], m0 = f_mins[0];
    float s1 = f_scales[1], m1 = f_mins[1];
    float s2 = f_scales[2], m2 = f_mins[2];

    for (int e = t; e < 512; e += 256) {
        F0s[e] = make_float2(q_f0[2*e]*s0 + m0, q_f0[2*e+1]*s0 + m0);
        F1s[e] = make_float2(q_f1[2*e]*s1 + m1, q_f1[2*e+1]*s1 + m1);
    }
    {   // phase 1: C2[i,j] = sum_k CL[d][k][ij] * F2[c,k]   (coalesced reads)
        float2 acc = make_float2(0.f, 0.f);
#pragma unroll
        for (int k = 0; k < 16; ++k) {
            float2 clv = CL[(d*16 + k)*256 + t];
            float2 f2 = make_float2(q_f2[(c*16+k)*2]*s2 + m2,
                                    q_f2[(c*16+k)*2+1]*s2 + m2);
            acc = cfma(clv, f2, acc);
        }
        __syncthreads();
        C2p[(t >> 4)*17 + (t & 15)] = acc;
    }
    __syncthreads();
#pragma unroll
    for (int r = 0; r < 2; ++r) {   // phase 2: A2[i,b] = sum_j C2[i,j]*F1[b,j]
        int e = t + r*256; int i = e & 15, b = e >> 4;
        float2 acc = make_float2(0.f, 0.f);
#pragma unroll
        for (int j = 0; j < 16; ++j)
            acc = cfma(C2p[i*17 + j], F1s[b*16 + j], acc);
        A2p[i*33 + b] = acc;
    }
    __syncthreads();
    {   // phase 3: W4[m,a,b] = sum_i F0[a,i]*A2[i,b]
        int b = t & 31, a0 = t >> 5;
#pragma unroll
        for (int q = 0; q < 4; ++q) {
            int a = a0 + 8*q;
            float2 acc = make_float2(0.f, 0.f);
#pragma unroll
            for (int i = 0; i < 16; ++i)
                acc = cfma(F0s[a*16 + i], A2p[i*33 + b], acc);
            W4[m*1024 + a*32 + b] = acc;
        }
    }
}

// ============ fwd_h body: partial DFT along h ============
__device__ __forceinline__ void fwdh_body(
    int bid, const float2* __restrict__ A1, float2* __restrict__ X)
{
    __shared__ float2 tbl[256];
    __shared__ float as_re[8*264];
    __shared__ float as_im[8*264];
    int tid = threadIdx.x;
    int ky = bid >> 5, bi0 = (bid & 31) * 8;
    tbl[tid] = make_float2(cospif(tid * (1.f/128.f)), -sinpif(tid * (1.f/128.f)));
    for (int idx = tid; idx < 2048; idx += 256) {
        int b = idx >> 8, h = idx & 255;
        float2 v = A1[ky*65536 + (bi0 + b)*256 + h];
        int ad = (h >> 5)*264 + (h & 31)*8 + b;
        as_re[ad] = v.x; as_im[ad] = v.y;
    }
    __syncthreads();
    int lane = tid & 63, g = tid >> 6;
    int bl = lane & 7, q = lane >> 3;
    int kx0 = g * 8;
    float2 acc[8];
#pragma unroll
    for (int j = 0; j < 8; ++j) acc[j] = make_float2(0.f, 0.f);
    int base = q*264 + bl;
    for (int hh = 0; hh < 32; ++hh) {
        float ar = as_re[base + hh*8];
        float ai = as_im[base + hh*8];
#pragma unroll
        for (int j = 0; j < 8; ++j) {
            int kk = kx0 + j + 112;
            float2 t = tbl[(kk * hh) & 255];      // wave-uniform broadcast
            acc[j].x = fmaf(ar, t.x, fmaf(-ai, t.y, acc[j].x));
            acc[j].y = fmaf(ar, t.y, fmaf( ai, t.x, acc[j].y));
        }
    }
    float2 fstep = tbl[q * 32];                   // e^{-2pi i q/8}
    float2 f = make_float2(1.f, 0.f);
#pragma unroll
    for (int j = 0; j < 8; ++j) {
        float2 v = cmul(acc[j], f);
        v.x += __shfl_xor(v.x, 8);  v.y += __shfl_xor(v.y, 8);
        v.x += __shfl_xor(v.x, 16); v.y += __shfl_xor(v.y, 16);
        v.x += __shfl_xor(v.x, 32); v.y += __shfl_xor(v.y, 32);
        acc[j] = v;
        f = cmul(f, fstep);
    }
    if (q == 0) {
        const float inv = 1.f / 65536.f;
#pragma unroll
        for (int j = 0; j < 8; ++j)
            X[((kx0 + j)*17 + ky)*256 + bi0 + bl] =
                make_float2(acc[j].x * inv, acc[j].y * inv);
    }
}

// ============ K2 = weights ∪ fwd_h (both depend only on K1) ============
__global__ __launch_bounds__(256) void k2_kernel(
    const float2* __restrict__ CL, const int* __restrict__ q_f0,
    const int* __restrict__ q_f1, const int* __restrict__ q_f2,
    const float* __restrict__ f_scales, const float* __restrict__ f_mins,
    float2* __restrict__ W4, const float2* __restrict__ A1,
    float2* __restrict__ X)
{
    if (blockIdx.x < 544)
        weights_body(blockIdx.x, CL, q_f0, q_f1, q_f2, f_scales, f_mins, W4);
    else
        fwdh_body(blockIdx.x - 544, A1, X);
}

// ================= per-mode channel mixing =================
__global__ __launch_bounds__(256) void mix_kernel(const float2* __restrict__ X,
                                                  const float2* __restrict__ W4,
                                                  float2* __restrict__ Mx)
{
    __shared__ float2 Xs[256];
    __shared__ float2 Ws[1024];
    int tid = threadIdx.x, mode = blockIdx.x;
    Xs[tid] = X[mode*256 + tid];
    for (int idx = tid; idx < 1024; idx += 256) Ws[idx] = W4[mode*1024 + idx];
    __syncthreads();
    int b = tid >> 5, o = tid & 31;
    float2 acc = make_float2(0.f, 0.f);
#pragma unroll
    for (int i = 0; i < 32; ++i)
        acc = cfma(Xs[b*32 + i], Ws[i*32 + o], acc);
    Mx[mode*256 + tid] = acc;
}

// ================= fused inverse =================
// Grid 1024 = bo(256, major) x hcg(4); 512 threads; each block stages ms ONCE
// and processes 2 hc chunks (waves 0-3 chunk A, waves 4-7 chunk B). bo-major
// order keeps sibling blocks' scattered Mx column L2-warm. Phase 1 uses the
// wave-uniform runtime-ky scheme (ks = lane>>5 half-wave ky slot).
__global__ __launch_bounds__(512) void inv_kernel(const float2* __restrict__ Mx,
                                                  const int* __restrict__ q_bias,
                                                  const float* __restrict__ b_scale,
                                                  const float* __restrict__ b_min,
                                                  float* __restrict__ out)
{
    __shared__ float2 ms[544];
    __shared__ __align__(16) float2 Ts[2][32*18];  // [chunk][rows padded to 18]
    int tid = threadIdx.x;
    int bo = blockIdx.x >> 2, hcg = blockIdx.x & 3;
    for (int idx = tid; idx < 544; idx += 512) ms[idx] = Mx[idx*256 + bo];
    __syncthreads();
    {   // phase 1: Ts[grp][hh][ky] = sum_kx ms[kx][ky] e^{+2pi i (kx+112)h/256}
        int lane = tid & 63;
        int w = (tid >> 6) & 3;                    // wave within group
        int grp = tid >> 8;                        // chunk 0/1
        int hh = lane & 31, ks = lane >> 5;        // ky slot 0/1
        int h = (hcg*2 + grp)*32 + hh;
        int n0 = (112 * h) & 255;
        float tr = cospif(n0 * (1.f/128.f)), ti = sinpif(n0 * (1.f/128.f));
        float sr = cospif(h  * (1.f/128.f)), si = sinpif(h  * (1.f/128.f));
        float2* Tg = Ts[grp];
        if (w < 3) {                               // ky = 4w+ks, 4w+ks+2
            int ky0 = 4*w + ks;
            float2 a0 = make_float2(0.f,0.f), a1 = make_float2(0.f,0.f);
            for (int kx = 0; kx < 32; ++kx) {
                const float2* mr = ms + kx*17;
                float2 v0 = mr[ky0], v1 = mr[ky0+2];
                a0.x = fmaf(v0.x, tr, fmaf(-v0.y, ti, a0.x));
                a0.y = fmaf(v0.x, ti, fmaf( v0.y, tr, a0.y));
                a1.x = fmaf(v1.x, tr, fmaf(-v1.y, ti, a1.x));
                a1.y = fmaf(v1.x, ti, fmaf( v1.y, tr, a1.y));
                float ntr = fmaf(tr, sr, -ti*si);
                ti = fmaf(tr, si, ti*sr);
                tr = ntr;
            }
            Tg[hh*18 + ky0]     = a0;
            Tg[hh*18 + ky0 + 2] = a1;
        } else {                                   // ky = 12+ks, 14+ks, (16)
            int ky0 = 12 + ks;
            int ky2 = ky0 + 4, ky2c = ky2 > 16 ? 16 : ky2;
            float2 a0 = make_float2(0.f,0.f), a1 = make_float2(0.f,0.f),
                   a2 = make_float2(0.f,0.f);
            for (int kx = 0; kx < 32; ++kx) {
                const float2* mr = ms + kx*17;
                float2 v0 = mr[ky0], v1 = mr[ky0+2], v2 = mr[ky2c];
                a0.x = fmaf(v0.x, tr, fmaf(-v0.y, ti, a0.x));
                a0.y = fmaf(v0.x, ti, fmaf( v0.y, tr, a0.y));
                a1.x = fmaf(v1.x, tr, fmaf(-v1.y, ti, a1.x));
                a1.y = fmaf(v1.x, ti, fmaf( v1.y, tr, a1.y));
                a2.x = fmaf(v2.x, tr, fmaf(-v2.y, ti, a2.x));
                a2.y = fmaf(v2.x, ti, fmaf( v2.y, tr, a2.y));
                float ntr = fmaf(tr, sr, -ti*si);
                ti = fmaf(tr, si, ti*sr);
                tr = ntr;
            }
            Tg[hh*18 + ky0]     = a0;
            Tg[hh*18 + ky0 + 2] = a1;
            if (ky2 < 17) Tg[hh*18 + ky2] = a2;
        }
    }
    __syncthreads();
    {   // phase 2: out[h][w0+64q] = 2*Re(T[h]*e^{i th0}*i^{ky*q}) + bias
        int w0 = tid & 63, hs = (tid >> 6) & 3, grp = tid >> 8;
        int hc = hcg*2 + grp;
        const float2* Tg = Ts[grp];
        float C[17], S[17];
        {
            int n0 = (56 * w0) & 255;
            float tr = cospif(n0 * (1.f/128.f)), ti = sinpif(n0 * (1.f/128.f));
            float sr = cospif(w0 * (1.f/128.f)), si = sinpif(w0 * (1.f/128.f));
#pragma unroll
            for (int ky = 0; ky < 17; ++ky) {
                C[ky] = tr; S[ky] = ti;
                float ntr = fmaf(tr, sr, -ti*si);
                ti = fmaf(tr, si, ti*sr);
                tr = ntr;
            }
        }
        float bias = q_bias[bo & 31] * (*b_scale) + (*b_min);
        float* obase = out + (size_t)bo*65536 + (size_t)hc*32*256;

#pragma unroll
        for (int r = 0; r < 8; ++r) {
            int hh = hs*8 + r;
            const float4* tp = (const float4*)&Tg[hh*18];
            float R0 = 0.f, R1 = 0.f, R2 = 0.f, R3 = 0.f, I1 = 0.f, I3 = 0.f;
#pragma unroll
            for (int kp = 0; kp < 9; ++kp) {
                float vx0, vy0, vx1 = 0.f, vy1 = 0.f;
                if (kp < 8) {
                    float4 v4 = tp[kp];
                    vx0 = v4.x; vy0 = v4.y; vx1 = v4.z; vy1 = v4.w;
                } else {
                    float2 v2 = Tg[hh*18 + 16];
                    vx0 = v2.x; vy0 = v2.y;
                }
#pragma unroll
                for (int half = 0; half < 2; ++half) {
                    if (kp == 8 && half == 1) break;
                    const int ky = 2*kp + half;
                    float vx = half ? vx1 : vx0;
                    float vy = half ? vy1 : vy0;
                    float ur = fmaf(vx, C[ky], -vy*S[ky]);
                    if ((ky & 1) == 0) {
                        if ((ky & 3) == 0) R0 += ur; else R2 += ur;
                    } else {
                        float ui = fmaf(vx, S[ky], vy*C[ky]);
                        if ((ky & 3) == 1) { R1 += ur; I1 += ui; }
                        else               { R3 += ur; I3 += ui; }
                    }
                }
            }
            float e02 = R0 + R2, d02 = R0 - R2;
            float e13 = R1 + R3, di  = I3 - I1;
            float q0 = e02 + e13, q2 = e02 - e13;
            float q1 = d02 + di,  q3 = d02 - di;
            obase[hh*256 + w0]       = fmaf(2.f, q0, bias);
            obase[hh*256 + w0 + 64]  = fmaf(2.f, q1, bias);
            obase[hh*256 + w0 + 128] = fmaf(2.f, q2, bias);
            obase[hh*256 + w0 + 192] = fmaf(2.f, q3, bias);
        }
    }
}

extern "C" void kernel_launch(void* const* d_in, const int* in_sizes, int n_in,
                              void* d_out, int out_size, void* d_ws, size_t ws_size,
                              hipStream_t stream) {
    const float* x          = (const float*)d_in[0];
    const float* core_scale = (const float*)d_in[1];
    const float* core_min   = (const float*)d_in[2];
    const float* f_scales   = (const float*)d_in[3];
    const float* f_mins     = (const float*)d_in[4];
    const float* b_scale    = (const float*)d_in[5];
    const float* b_min      = (const float*)d_in[6];
    const int* q_core = (const int*)d_in[7];
    const int* q_f0   = (const int*)d_in[8];
    const int* q_f1   = (const int*)d_in[9];
    const int* q_f2   = (const int*)d_in[10];
    const int* q_f3   = (const int*)d_in[11];
    const int* q_bias = (const int*)d_in[12];
    float* out = (float*)d_out;

    float2* ws = (float2*)d_ws;
    float2* A1 = ws;                 // 1,114,112  [17][256 bi][256 h]
    float2* W4 = ws + 1114112;       //   557,056  [544][32][32]
    float2* X  = W4 + 557056;        //   139,264  [544][256]
    float2* Mx = X + 139264;         //   139,264  [544][256]
    float2* CL = Mx + 139264;        //    69,632  [17][16][256]
    (void)ws_size; (void)n_in; (void)in_sizes; (void)out_size;

    k1_kernel<<<1296, 256, 0, stream>>>(q_core, q_f3, core_scale, core_min,
                                        f_scales, f_mins, CL, x, A1);
    k2_kernel<<<1088, 256, 0, stream>>>(CL, q_f0, q_f1, q_f2,
                                        f_scales, f_mins, W4, A1, X);
    mix_kernel<<<544, 256, 0, stream>>>(X, W4, Mx);
    inv_kernel<<<1024, 512, 0, stream>>>(Mx, q_bias, b_scale, b_min, out);
}